// Round 1
// baseline (1448.674 us; speedup 1.0000x reference)
//
#include <hip/hip_runtime.h>
#include <hip/hip_bf16.h>
#include <math.h>

#define NO_N 100000
#define NR_N 1000
#define E_N  1000000

// ---------------------------------------------------------------------------
// prep: q[r,h], skip[r,h], t[r,d] = sum_h We[d,h]*q[r,h]
// ---------------------------------------------------------------------------
__global__ __launch_bounds__(256) void k_prep_rider(
    const float* __restrict__ xr,
    const float* __restrict__ Wq, const float* __restrict__ bq,
    const float* __restrict__ Wskip, const float* __restrict__ bskip,
    const float* __restrict__ We,
    float* __restrict__ q, float* __restrict__ skip, float* __restrict__ t)
{
    __shared__ float sx[4][32];
    __shared__ float sq[4][64];
    int tid = threadIdx.x;
    int rbase = blockIdx.x * 4;
    if (tid < 128) {
        int rl = tid >> 5, d = tid & 31;
        int r = rbase + rl;
        sx[rl][d] = (r < NR_N) ? xr[r * 32 + d] : 0.f;
    }
    __syncthreads();
    int rl = tid >> 6, h = tid & 63;
    int r = rbase + rl;
    float aq = bq[h], as = bskip[h];
    #pragma unroll 4
    for (int d = 0; d < 32; ++d) {
        float xv = sx[rl][d];
        aq += xv * Wq[d * 64 + h];
        as += xv * Wskip[d * 64 + h];
    }
    sq[rl][h] = aq;
    if (r < NR_N) { q[r * 64 + h] = aq; skip[r * 64 + h] = as; }
    __syncthreads();
    if (tid < 16) {
        int rl2 = tid >> 2, d = tid & 3;
        int r2 = rbase + rl2;
        float acc = 0.f;
        for (int hh = 0; hh < 64; ++hh) acc += We[d * 64 + hh] * sq[rl2][hh];
        if (r2 < NR_N) t[r2 * 4 + d] = acc;
    }
}

// b1eff[c] = b1[c] + sum_j omega[j] * W1[128+j][c]   (omega rows folded out)
__global__ __launch_bounds__(128) void k_prep_b1eff(
    const float* __restrict__ W1, const float* __restrict__ b1,
    const float* __restrict__ omega, float* __restrict__ b1eff)
{
    int c = threadIdx.x;
    float acc = b1[c];
    #pragma unroll 4
    for (int j = 0; j < 32; ++j) acc += omega[j] * W1[(128 + j) * 128 + c];
    b1eff[c] = acc;
}

// ---------------------------------------------------------------------------
// k,v,p = x_order @ {Wk,Wv,Wp} + bias    [100000 x 64] each
// one wave per row; W matrices in LDS; x row broadcast from LDS
// ---------------------------------------------------------------------------
__global__ __launch_bounds__(256) void k_kvp(
    const float* __restrict__ x,
    const float* __restrict__ Wk, const float* __restrict__ bk,
    const float* __restrict__ Wv, const float* __restrict__ bv,
    const float* __restrict__ Wp, const float* __restrict__ bp,
    float* __restrict__ ok, float* __restrict__ ov, float* __restrict__ op)
{
    __shared__ __align__(16) float sWk[4096];
    __shared__ __align__(16) float sWv[4096];
    __shared__ __align__(16) float sWp[4096];
    __shared__ float sx[4][64];
    int tid = threadIdx.x;
    {
        const float4* a = (const float4*)Wk;
        const float4* b = (const float4*)Wv;
        const float4* c = (const float4*)Wp;
        float4* A = (float4*)sWk; float4* B = (float4*)sWv; float4* C = (float4*)sWp;
        for (int i = tid; i < 1024; i += 256) { A[i] = a[i]; B[i] = b[i]; C[i] = c[i]; }
    }
    __syncthreads();
    int wave = tid >> 6, lane = tid & 63;
    float bkl = bk[lane], bvl = bv[lane], bpl = bp[lane];
    int gw = blockIdx.x * 4 + wave;
    int stride = gridDim.x * 4;
    for (int row = gw; row < NO_N; row += stride) {
        sx[wave][lane] = x[(size_t)row * 64 + lane];   // wave-private tile, no barrier
        float ak = bkl, av = bvl, ap = bpl;
        #pragma unroll 8
        for (int d = 0; d < 64; ++d) {
            float xd = sx[wave][d];
            ak = fmaf(xd, sWk[d * 64 + lane], ak);
            av = fmaf(xd, sWv[d * 64 + lane], av);
            ap = fmaf(xd, sWp[d * 64 + lane], ap);
        }
        size_t o = (size_t)row * 64 + lane;
        ok[o] = ak; ov[o] = av; op[o] = ap;
    }
}

// ---------------------------------------------------------------------------
// CSR build: histogram -> scan -> scatter
// ---------------------------------------------------------------------------
__global__ __launch_bounds__(256) void k_hist(const int* __restrict__ ridx,
                                              int* __restrict__ counts)
{
    __shared__ int hc[NR_N];
    int tid = threadIdx.x;
    for (int i = tid; i < NR_N; i += 256) hc[i] = 0;
    __syncthreads();
    int stride = gridDim.x * 256;
    for (int e = blockIdx.x * 256 + tid; e < E_N; e += stride)
        atomicAdd(&hc[ridx[e]], 1);
    __syncthreads();
    for (int i = tid; i < NR_N; i += 256)
        if (hc[i]) atomicAdd(&counts[i], hc[i]);
}

__global__ __launch_bounds__(1024) void k_scan(const int* __restrict__ counts,
                                               int* __restrict__ offsets,
                                               int* __restrict__ cursor)
{
    __shared__ int s[1024];
    int tid = threadIdx.x;
    int c = (tid < NR_N) ? counts[tid] : 0;
    s[tid] = c;
    __syncthreads();
    for (int off = 1; off < 1024; off <<= 1) {
        int tv = (tid >= off) ? s[tid - off] : 0;
        __syncthreads();
        s[tid] += tv;
        __syncthreads();
    }
    if (tid < NR_N) {
        int ex = s[tid] - c;          // exclusive
        offsets[tid] = ex;
        cursor[tid] = ex;
    }
    if (tid == NR_N - 1) offsets[NR_N] = s[tid];
}

__global__ __launch_bounds__(256) void k_scatter(const int* __restrict__ ridx,
                                                 int* __restrict__ cursor,
                                                 int* __restrict__ sorted)
{
    int stride = gridDim.x * 256;
    for (int e = blockIdx.x * 256 + threadIdx.x; e < E_N; e += stride) {
        int pos = atomicAdd(&cursor[ridx[e]], 1);
        sorted[pos] = e;
    }
}

// ---------------------------------------------------------------------------
// rider embedding: block per rider; wave-cooperative edge processing.
// alpha = (q.k[o] + ea.t[r]) * 0.125 ; softmax without max-sub (alpha ~ O(1))
// emb = (sum ex*v[o] + (sum ex*ea)@We) / sum ex + skip
// ---------------------------------------------------------------------------
__global__ __launch_bounds__(1024) void k_rider(
    const int* __restrict__ offsets, const int* __restrict__ sorted,
    const int* __restrict__ oidx, const float* __restrict__ ea,
    const float* __restrict__ q, const float* __restrict__ t,
    const float* __restrict__ kk, const float* __restrict__ vv,
    const float* __restrict__ We, const float* __restrict__ skip,
    float* __restrict__ emb)
{
    int r = blockIdx.x;
    int wave = threadIdx.x >> 6, lane = threadIdx.x & 63;
    int beg = offsets[r], end = offsets[r + 1];
    float ql = q[r * 64 + lane];
    float tl = (lane < 4) ? t[r * 4 + lane] : 0.f;
    float aggv = 0.f, agge = 0.f, dsum = 0.f;
    for (int j = beg + wave; j < end; j += 16) {
        int e = sorted[j];
        int o = oidx[e];
        float kl = kk[(size_t)o * 64 + lane];
        float eal = (lane < 4) ? ea[(size_t)e * 4 + lane] : 0.f;
        float c = fmaf(ql, kl, tl * eal);
        #pragma unroll
        for (int m = 1; m < 64; m <<= 1) c += __shfl_xor(c, m);
        float exv = __expf(c * 0.125f);
        dsum += exv;
        aggv = fmaf(exv, vv[(size_t)o * 64 + lane], aggv);
        agge = fmaf(exv, eal, agge);
    }
    __shared__ float rv[16][64];
    __shared__ float re4[16][4];
    __shared__ float rd[16];
    rv[wave][lane] = aggv;
    if (lane < 4) re4[wave][lane] = agge;
    if (lane == 0) rd[wave] = dsum;
    __syncthreads();
    if (threadIdx.x < 64) {
        int l = threadIdx.x;
        float av = 0.f, ds = 0.f, a0 = 0.f, a1 = 0.f, a2 = 0.f, a3 = 0.f;
        #pragma unroll 4
        for (int w = 0; w < 16; ++w) {
            av += rv[w][l]; ds += rd[w];
            a0 += re4[w][0]; a1 += re4[w][1]; a2 += re4[w][2]; a3 += re4[w][3];
        }
        float corr = a0 * We[0 * 64 + l] + a1 * We[1 * 64 + l]
                   + a2 * We[2 * 64 + l] + a3 * We[3 * 64 + l];
        emb[r * 64 + l] = (av + corr) / (ds + 1e-16f) + skip[r * 64 + l];
    }
}

// ---------------------------------------------------------------------------
// per-edge scoring: out = clip(0.125*dot(oe,re) + relu([oe re]@W1[:128]+b1eff)@W2 + b2)
// 64-edge tile; k split in two 64-chunks (oe chunk, re chunk) to stay <64KB LDS.
// ---------------------------------------------------------------------------
__global__ __launch_bounds__(512) void k_edge(
    const int* __restrict__ oidx, const int* __restrict__ ridx,
    const float* __restrict__ p, const float* __restrict__ emb,
    const float* __restrict__ W1, const float* __restrict__ b1eff,
    const float* __restrict__ W2, const float* __restrict__ b2,
    float* __restrict__ out)
{
    __shared__ __align__(16) float sW1[64 * 128];   // one 64-row k-chunk, 32KB
    __shared__ float sRI[64][65];                   // 64 edges x 64 dims (+1 pad)
    int tid = threadIdx.x;
    int cg = (tid & 15) * 8;        // 8 output cols
    int e0 = (tid >> 4) * 2;        // 2 edges
    int e1 = e0 + 1;
    int g4 = (tid & 15) * 4;        // 4-elem slice of the 64-dot
    float w2r[8], b1r[8];
    #pragma unroll
    for (int i = 0; i < 8; ++i) { w2r[i] = W2[cg + i]; b1r[i] = b1eff[cg + i]; }
    float b2v = b2[0];
    const float4* W1v = (const float4*)W1;
    float4* sW1v = (float4*)sW1;

    for (int tile = blockIdx.x; tile < E_N / 64; tile += gridDim.x) {
        int ebase = tile * 64;
        // ---- chunk 0: oe = p[order_idx], W1 rows 0..63 ----
        __syncthreads();
        for (int idx = tid; idx < 64 * 64; idx += 512) {
            int el = idx >> 6, d = idx & 63;
            int o = oidx[ebase + el];
            sRI[el][d] = p[(size_t)o * 64 + d];
        }
        for (int i = tid; i < 2048; i += 512) sW1v[i] = W1v[i];
        __syncthreads();
        float acc0[8], acc1[8];
        #pragma unroll
        for (int i = 0; i < 8; ++i) { acc0[i] = b1r[i]; acc1[i] = b1r[i]; }
        #pragma unroll 4
        for (int k = 0; k < 64; ++k) {
            const float* wrow = &sW1[k * 128 + cg];
            float r0 = sRI[e0][k], r1 = sRI[e1][k];
            #pragma unroll
            for (int i = 0; i < 8; ++i) {
                float w = wrow[i];
                acc0[i] = fmaf(r0, w, acc0[i]);
                acc1[i] = fmaf(r1, w, acc1[i]);
            }
        }
        float oe0[4], oe1[4];
        #pragma unroll
        for (int i = 0; i < 4; ++i) { oe0[i] = sRI[e0][g4 + i]; oe1[i] = sRI[e1][g4 + i]; }
        // ---- chunk 1: re = emb[rider_idx], W1 rows 64..127 ----
        __syncthreads();
        for (int idx = tid; idx < 64 * 64; idx += 512) {
            int el = idx >> 6, d = idx & 63;
            int rr = ridx[ebase + el];
            sRI[el][d] = emb[rr * 64 + d];
        }
        for (int i = tid; i < 2048; i += 512) sW1v[i] = W1v[2048 + i];
        __syncthreads();
        #pragma unroll 4
        for (int k = 0; k < 64; ++k) {
            const float* wrow = &sW1[k * 128 + cg];
            float r0 = sRI[e0][k], r1 = sRI[e1][k];
            #pragma unroll
            for (int i = 0; i < 8; ++i) {
                float w = wrow[i];
                acc0[i] = fmaf(r0, w, acc0[i]);
                acc1[i] = fmaf(r1, w, acc1[i]);
            }
        }
        float d0 = 0.f, d1 = 0.f;
        #pragma unroll
        for (int i = 0; i < 4; ++i) {
            d0 = fmaf(oe0[i], sRI[e0][g4 + i], d0);
            d1 = fmaf(oe1[i], sRI[e1][g4 + i], d1);
        }
        float p0 = 0.125f * d0, p1 = 0.125f * d1;
        #pragma unroll
        for (int i = 0; i < 8; ++i) {
            p0 = fmaf(fmaxf(acc0[i], 0.f), w2r[i], p0);
            p1 = fmaf(fmaxf(acc1[i], 0.f), w2r[i], p1);
        }
        #pragma unroll
        for (int m = 1; m < 16; m <<= 1) {
            p0 += __shfl_xor(p0, m);
            p1 += __shfl_xor(p1, m);
        }
        if ((tid & 15) == 0) {
            out[ebase + e0] = fminf(fmaxf(p0 + b2v, -10.f), 10.f);
            out[ebase + e1] = fminf(fmaxf(p1 + b2v, -10.f), 10.f);
        }
    }
}

// ---------------------------------------------------------------------------
extern "C" void kernel_launch(void* const* d_in, const int* in_sizes, int n_in,
                              void* d_out, int out_size, void* d_ws, size_t ws_size,
                              hipStream_t stream)
{
    const float* x_order   = (const float*)d_in[0];
    const float* x_rider   = (const float*)d_in[1];
    const float* edge_attr = (const float*)d_in[2];
    const int*   order_idx = (const int*)d_in[3];
    const int*   rider_idx = (const int*)d_in[4];
    const float* omega     = (const float*)d_in[5];
    const float* Wk = (const float*)d_in[6];  const float* bk = (const float*)d_in[7];
    const float* Wq = (const float*)d_in[8];  const float* bq = (const float*)d_in[9];
    const float* Wv = (const float*)d_in[10]; const float* bv = (const float*)d_in[11];
    const float* We = (const float*)d_in[12];
    const float* Wskip = (const float*)d_in[13]; const float* bskip = (const float*)d_in[14];
    const float* Wp = (const float*)d_in[15]; const float* bp = (const float*)d_in[16];
    const float* W1 = (const float*)d_in[17]; const float* b1 = (const float*)d_in[18];
    const float* W2 = (const float*)d_in[19]; const float* b2 = (const float*)d_in[20];
    float* out = (float*)d_out;

    float* wsf     = (float*)d_ws;
    float* ws_k    = wsf;
    float* ws_v    = ws_k + (size_t)NO_N * 64;
    float* ws_p    = ws_v + (size_t)NO_N * 64;
    float* ws_q    = ws_p + (size_t)NO_N * 64;
    float* ws_skip = ws_q + NR_N * 64;
    float* ws_emb  = ws_skip + NR_N * 64;
    float* ws_t    = ws_emb + NR_N * 64;
    float* ws_b1e  = ws_t + NR_N * 4;
    int* ws_counts  = (int*)(ws_b1e + 128);
    int* ws_offsets = ws_counts + NR_N;
    int* ws_cursor  = ws_offsets + NR_N + 8;
    int* ws_sorted  = ws_cursor + NR_N;

    hipMemsetAsync(ws_counts, 0, NR_N * sizeof(int), stream);

    k_prep_rider<<<NR_N / 4, 256, 0, stream>>>(x_rider, Wq, bq, Wskip, bskip, We,
                                               ws_q, ws_skip, ws_t);
    k_prep_b1eff<<<1, 128, 0, stream>>>(W1, b1, omega, ws_b1e);
    k_kvp<<<1024, 256, 0, stream>>>(x_order, Wk, bk, Wv, bv, Wp, bp, ws_k, ws_v, ws_p);
    k_hist<<<512, 256, 0, stream>>>(rider_idx, ws_counts);
    k_scan<<<1, 1024, 0, stream>>>(ws_counts, ws_offsets, ws_cursor);
    k_scatter<<<512, 256, 0, stream>>>(rider_idx, ws_cursor, ws_sorted);
    k_rider<<<NR_N, 1024, 0, stream>>>(ws_offsets, ws_sorted, order_idx, edge_attr,
                                       ws_q, ws_t, ws_k, ws_v, We, ws_skip, ws_emb);
    k_edge<<<2048, 512, 0, stream>>>(order_idx, rider_idx, ws_p, ws_emb,
                                     W1, ws_b1e, W2, b2, out);
}

// Round 2
// 652.912 us; speedup vs baseline: 2.2188x; 2.2188x over previous
//
#include <hip/hip_runtime.h>
#include <hip/hip_bf16.h>
#include <math.h>

#define NO_N 100000
#define NR_N 1000
#define E_N  1000000

typedef short bf16x8 __attribute__((ext_vector_type(8)));
typedef float floatx4 __attribute__((ext_vector_type(4)));

__device__ __forceinline__ unsigned short bfu(float x) {
    union { __hip_bfloat16 h; unsigned short u; } c;
    c.h = __float2bfloat16(x);
    return c.u;
}

// ---------------------------------------------------------------------------
// prep: q[r,h], skip[r,h], t[r,d] = sum_h We[d,h]*q[r,h]
// ---------------------------------------------------------------------------
__global__ __launch_bounds__(256) void k_prep_rider(
    const float* __restrict__ xr,
    const float* __restrict__ Wq, const float* __restrict__ bq,
    const float* __restrict__ Wskip, const float* __restrict__ bskip,
    const float* __restrict__ We,
    float* __restrict__ q, float* __restrict__ skip, float* __restrict__ t)
{
    __shared__ float sx[4][32];
    __shared__ float sq[4][64];
    int tid = threadIdx.x;
    int rbase = blockIdx.x * 4;
    if (tid < 128) {
        int rl = tid >> 5, d = tid & 31;
        int r = rbase + rl;
        sx[rl][d] = (r < NR_N) ? xr[r * 32 + d] : 0.f;
    }
    __syncthreads();
    int rl = tid >> 6, h = tid & 63;
    int r = rbase + rl;
    float aq = bq[h], as = bskip[h];
    #pragma unroll 4
    for (int d = 0; d < 32; ++d) {
        float xv = sx[rl][d];
        aq += xv * Wq[d * 64 + h];
        as += xv * Wskip[d * 64 + h];
    }
    sq[rl][h] = aq;
    if (r < NR_N) { q[r * 64 + h] = aq; skip[r * 64 + h] = as; }
    __syncthreads();
    if (tid < 16) {
        int rl2 = tid >> 2, d = tid & 3;
        int r2 = rbase + rl2;
        float acc = 0.f;
        for (int hh = 0; hh < 64; ++hh) acc += We[d * 64 + hh] * sq[rl2][hh];
        if (r2 < NR_N) t[r2 * 4 + d] = acc;
    }
}

// b1eff[c] = b1[c] + sum_j omega[j] * W1[128+j][c]
__global__ __launch_bounds__(128) void k_prep_b1eff(
    const float* __restrict__ W1, const float* __restrict__ b1,
    const float* __restrict__ omega, float* __restrict__ b1eff)
{
    int c = threadIdx.x;
    float acc = b1[c];
    #pragma unroll 4
    for (int j = 0; j < 32; ++j) acc += omega[j] * W1[(128 + j) * 128 + c];
    b1eff[c] = acc;
}

// ---------------------------------------------------------------------------
// kv packed bf16 (k | v<<16) and p f32 = x_order @ {Wk,Wv,Wp} + bias
// ---------------------------------------------------------------------------
__global__ __launch_bounds__(256) void k_kvp(
    const float* __restrict__ x,
    const float* __restrict__ Wk, const float* __restrict__ bk,
    const float* __restrict__ Wv, const float* __restrict__ bv,
    const float* __restrict__ Wp, const float* __restrict__ bp,
    unsigned int* __restrict__ okv, float* __restrict__ op)
{
    __shared__ __align__(16) float sWk[4096];
    __shared__ __align__(16) float sWv[4096];
    __shared__ __align__(16) float sWp[4096];
    __shared__ float sx[4][64];
    int tid = threadIdx.x;
    {
        const float4* a = (const float4*)Wk;
        const float4* b = (const float4*)Wv;
        const float4* c = (const float4*)Wp;
        float4* A = (float4*)sWk; float4* B = (float4*)sWv; float4* C = (float4*)sWp;
        for (int i = tid; i < 1024; i += 256) { A[i] = a[i]; B[i] = b[i]; C[i] = c[i]; }
    }
    __syncthreads();
    int wave = tid >> 6, lane = tid & 63;
    float bkl = bk[lane], bvl = bv[lane], bpl = bp[lane];
    int gw = blockIdx.x * 4 + wave;
    int stride = gridDim.x * 4;
    for (int row = gw; row < NO_N; row += stride) {
        sx[wave][lane] = x[(size_t)row * 64 + lane];
        float ak = bkl, av = bvl, ap = bpl;
        #pragma unroll 8
        for (int d = 0; d < 64; ++d) {
            float xd = sx[wave][d];
            ak = fmaf(xd, sWk[d * 64 + lane], ak);
            av = fmaf(xd, sWv[d * 64 + lane], av);
            ap = fmaf(xd, sWp[d * 64 + lane], ap);
        }
        size_t o = (size_t)row * 64 + lane;
        okv[o] = (unsigned int)bfu(ak) | ((unsigned int)bfu(av) << 16);
        op[o] = ap;
    }
}

// ---------------------------------------------------------------------------
// CSR build: histogram -> scan -> scatter
// ---------------------------------------------------------------------------
__global__ __launch_bounds__(256) void k_hist(const int* __restrict__ ridx,
                                              int* __restrict__ counts)
{
    __shared__ int hc[NR_N];
    int tid = threadIdx.x;
    for (int i = tid; i < NR_N; i += 256) hc[i] = 0;
    __syncthreads();
    int stride = gridDim.x * 256;
    for (int e = blockIdx.x * 256 + tid; e < E_N; e += stride)
        atomicAdd(&hc[ridx[e]], 1);
    __syncthreads();
    for (int i = tid; i < NR_N; i += 256)
        if (hc[i]) atomicAdd(&counts[i], hc[i]);
}

__global__ __launch_bounds__(1024) void k_scan(const int* __restrict__ counts,
                                               int* __restrict__ offsets,
                                               int* __restrict__ cursor)
{
    __shared__ int s[1024];
    int tid = threadIdx.x;
    int c = (tid < NR_N) ? counts[tid] : 0;
    s[tid] = c;
    __syncthreads();
    for (int off = 1; off < 1024; off <<= 1) {
        int tv = (tid >= off) ? s[tid - off] : 0;
        __syncthreads();
        s[tid] += tv;
        __syncthreads();
    }
    if (tid < NR_N) {
        int ex = s[tid] - c;
        offsets[tid] = ex;
        cursor[tid] = ex;
    }
    if (tid == NR_N - 1) offsets[NR_N] = s[tid];
}

__global__ __launch_bounds__(256) void k_scatter(const int* __restrict__ ridx,
                                                 int* __restrict__ cursor,
                                                 int* __restrict__ sorted)
{
    int stride = gridDim.x * 256;
    for (int e = blockIdx.x * 256 + threadIdx.x; e < E_N; e += stride) {
        int pos = atomicAdd(&cursor[ridx[e]], 1);
        sorted[pos] = e;
    }
}

// ---------------------------------------------------------------------------
// rider embedding. Waves take contiguous edge chunks; 64 edge indices are
// batch-loaded then broadcast by __shfl (kills the sorted->oidx pointer chase).
// kv gathered as packed bf16 pairs (one 256B row instead of two).
// ---------------------------------------------------------------------------
__global__ __launch_bounds__(1024) void k_rider(
    const int* __restrict__ offsets, const int* __restrict__ sorted,
    const int* __restrict__ oidx, const float* __restrict__ ea,
    const float* __restrict__ q, const float* __restrict__ t,
    const unsigned int* __restrict__ kv,
    const float* __restrict__ We, const float* __restrict__ skip,
    float* __restrict__ emb)
{
    int r = blockIdx.x;
    int wave = threadIdx.x >> 6, lane = threadIdx.x & 63;
    int beg = offsets[r], end = offsets[r + 1];
    int cnt = end - beg;
    int chunk = (cnt + 15) >> 4;
    int s0 = beg + wave * chunk;
    int s1 = min(s0 + chunk, end);

    float ql = q[r * 64 + lane];
    float t0 = t[r * 4 + 0], t1 = t[r * 4 + 1], t2 = t[r * 4 + 2], t3 = t[r * 4 + 3];

    float aggv = 0.f, dsum = 0.f;
    float ag0 = 0.f, ag1 = 0.f, ag2 = 0.f, ag3 = 0.f;

    for (int jb = s0; jb < s1; jb += 64) {
        int j = jb + lane;
        bool valid = (j < s1);
        int ee = valid ? sorted[j] : 0;
        int oo = valid ? oidx[ee] : 0;
        float4 eav = make_float4(0.f, 0.f, 0.f, 0.f);
        if (valid) eav = *(const float4*)(ea + (size_t)ee * 4);
        float ealpha = eav.x * t0 + eav.y * t1 + eav.z * t2 + eav.w * t3;
        int nn = min(s1 - jb, 64);
        for (int i = 0; i < nn; ++i) {
            int o = __shfl(oo, i);
            unsigned int u = kv[(size_t)o * 64 + lane];
            float kl = __uint_as_float(u << 16);
            float vl = __uint_as_float(u & 0xffff0000u);
            float c = ql * kl;
            #pragma unroll
            for (int m = 1; m < 64; m <<= 1) c += __shfl_xor(c, m);
            c += __shfl(ealpha, i);
            float exv = __expf(c * 0.125f);
            dsum += exv;
            aggv = fmaf(exv, vl, aggv);
            float msk = (lane == i) ? exv : 0.f;
            ag0 = fmaf(msk, eav.x, ag0);
            ag1 = fmaf(msk, eav.y, ag1);
            ag2 = fmaf(msk, eav.z, ag2);
            ag3 = fmaf(msk, eav.w, ag3);
        }
    }
    // cross-lane sum of the per-lane agge partials
    #pragma unroll
    for (int m = 1; m < 64; m <<= 1) {
        ag0 += __shfl_xor(ag0, m);
        ag1 += __shfl_xor(ag1, m);
        ag2 += __shfl_xor(ag2, m);
        ag3 += __shfl_xor(ag3, m);
    }

    __shared__ float rv[16][64];
    __shared__ float re4[16][4];
    __shared__ float rd[16];
    rv[wave][lane] = aggv;
    if (lane == 0) {
        rd[wave] = dsum;
        re4[wave][0] = ag0; re4[wave][1] = ag1;
        re4[wave][2] = ag2; re4[wave][3] = ag3;
    }
    __syncthreads();
    if (threadIdx.x < 64) {
        int l = threadIdx.x;
        float av = 0.f, ds = 0.f, a0 = 0.f, a1 = 0.f, a2 = 0.f, a3 = 0.f;
        #pragma unroll 4
        for (int w = 0; w < 16; ++w) {
            av += rv[w][l]; ds += rd[w];
            a0 += re4[w][0]; a1 += re4[w][1]; a2 += re4[w][2]; a3 += re4[w][3];
        }
        float corr = a0 * We[0 * 64 + l] + a1 * We[1 * 64 + l]
                   + a2 * We[2 * 64 + l] + a3 * We[3 * 64 + l];
        emb[r * 64 + l] = (av + corr) / (ds + 1e-16f) + skip[r * 64 + l];
    }
}

// ---------------------------------------------------------------------------
// per-edge scoring via bf16 MFMA.
// A = [oe | re] (64 edges x 128 dims) staged in LDS as bf16 (stride 136).
// B = W1 (128x128) held as persistent register fragments: wave w owns cols
// [w*32, w*32+32). 16 ds_read_b128 + 32 MFMA per wave-tile.
// dot(oe,re) computed fp32 during staging. relu/W2 epilogue: xor-shuffle over
// the 16 cols of each tile, cross-wave sum via LDS.
// ---------------------------------------------------------------------------
__global__ __launch_bounds__(256, 4) void k_edge(
    const int* __restrict__ oidx, const int* __restrict__ ridx,
    const float* __restrict__ p, const float* __restrict__ emb,
    const float* __restrict__ W1, const float* __restrict__ b1eff,
    const float* __restrict__ W2, const float* __restrict__ b2,
    float* __restrict__ out)
{
    __shared__ __align__(16) unsigned short sA[64 * 136];
    __shared__ float sDot[64];
    __shared__ float sPart[4][64];

    const int tid = threadIdx.x;
    const int wave = tid >> 6;
    const int lane = tid & 63;
    const int l15 = lane & 15;
    const int quad = lane >> 4;

    // persistent B fragments: B[k][n] = W1[k][n]; lane holds n=l15(+16*ctl),
    // k = kc*32 + quad*8 + j
    bf16x8 bfr[2][4];
    float b1v[2], w2v[2];
    #pragma unroll
    for (int ctl = 0; ctl < 2; ++ctl) {
        int n = wave * 32 + ctl * 16 + l15;
        b1v[ctl] = b1eff[n];
        w2v[ctl] = W2[n];
        #pragma unroll
        for (int kc = 0; kc < 4; ++kc) {
            int k0 = kc * 32 + quad * 8;
            bf16x8 f;
            #pragma unroll
            for (int j = 0; j < 8; ++j)
                f[j] = (short)bfu(W1[(size_t)(k0 + j) * 128 + n]);
            bfr[ctl][kc] = f;
        }
    }
    float b2v = b2[0];

    const int el = tid >> 2;         // edge-in-tile 0..63
    const int qd = (tid & 3) * 16;   // dim base 0/16/32/48

    for (int tile = blockIdx.x; tile < E_N / 64; tile += gridDim.x) {
        int ebase = tile * 64;
        // ---- stage A tile + fp32 dot partials ----
        {
            int e = ebase + el;
            int o = oidx[e];
            int r = ridx[e];
            const float4* po = (const float4*)(p + (size_t)o * 64 + qd);
            const float4* pr = (const float4*)(emb + (size_t)r * 64 + qd);
            unsigned short* rowA = sA + el * 136;
            float dotp = 0.f;
            #pragma unroll
            for (int i = 0; i < 4; ++i) {
                float4 a = po[i];
                float4 b = pr[i];
                dotp += a.x * b.x + a.y * b.y + a.z * b.z + a.w * b.w;
                ushort4 ua = { bfu(a.x), bfu(a.y), bfu(a.z), bfu(a.w) };
                ushort4 ub = { bfu(b.x), bfu(b.y), bfu(b.z), bfu(b.w) };
                *(ushort4*)(rowA + qd + i * 4) = ua;
                *(ushort4*)(rowA + 64 + qd + i * 4) = ub;
            }
            dotp += __shfl_xor(dotp, 1);
            dotp += __shfl_xor(dotp, 2);
            if ((tid & 3) == 0) sDot[el] = dotp;
        }
        __syncthreads();

        // ---- MFMA: all 64 rows x this wave's 32 cols ----
        floatx4 acc[4][2];
        #pragma unroll
        for (int rt = 0; rt < 4; ++rt)
            #pragma unroll
            for (int ctl = 0; ctl < 2; ++ctl)
                acc[rt][ctl] = (floatx4){0.f, 0.f, 0.f, 0.f};

        #pragma unroll
        for (int rt = 0; rt < 4; ++rt) {
            const unsigned short* ar = sA + (size_t)(rt * 16 + l15) * 136 + quad * 8;
            bf16x8 a0 = *(const bf16x8*)(ar);
            bf16x8 a1 = *(const bf16x8*)(ar + 32);
            bf16x8 a2 = *(const bf16x8*)(ar + 64);
            bf16x8 a3 = *(const bf16x8*)(ar + 96);
            #pragma unroll
            for (int ctl = 0; ctl < 2; ++ctl) {
                floatx4 c = acc[rt][ctl];
                c = __builtin_amdgcn_mfma_f32_16x16x32_bf16(a0, bfr[ctl][0], c, 0, 0, 0);
                c = __builtin_amdgcn_mfma_f32_16x16x32_bf16(a1, bfr[ctl][1], c, 0, 0, 0);
                c = __builtin_amdgcn_mfma_f32_16x16x32_bf16(a2, bfr[ctl][2], c, 0, 0, 0);
                c = __builtin_amdgcn_mfma_f32_16x16x32_bf16(a3, bfr[ctl][3], c, 0, 0, 0);
                acc[rt][ctl] = c;
            }
        }

        // ---- epilogue: relu + W2, reduce over cols ----
        #pragma unroll
        for (int rt = 0; rt < 4; ++rt) {
            floatx4 s;
            #pragma unroll
            for (int g = 0; g < 4; ++g)
                s[g] = fmaxf(acc[rt][0][g] + b1v[0], 0.f) * w2v[0]
                     + fmaxf(acc[rt][1][g] + b1v[1], 0.f) * w2v[1];
            #pragma unroll
            for (int m = 1; m < 16; m <<= 1) {
                s[0] += __shfl_xor(s[0], m);
                s[1] += __shfl_xor(s[1], m);
                s[2] += __shfl_xor(s[2], m);
                s[3] += __shfl_xor(s[3], m);
            }
            if (l15 == 0) {
                int rowb = rt * 16 + quad * 4;
                sPart[wave][rowb + 0] = s[0];
                sPart[wave][rowb + 1] = s[1];
                sPart[wave][rowb + 2] = s[2];
                sPart[wave][rowb + 3] = s[3];
            }
        }
        __syncthreads();
        if (tid < 64) {
            float v = sPart[0][tid] + sPart[1][tid] + sPart[2][tid] + sPart[3][tid]
                    + 0.125f * sDot[tid] + b2v;
            out[ebase + tid] = fminf(fmaxf(v, -10.f), 10.f);
        }
        __syncthreads();
    }
}

// ---------------------------------------------------------------------------
extern "C" void kernel_launch(void* const* d_in, const int* in_sizes, int n_in,
                              void* d_out, int out_size, void* d_ws, size_t ws_size,
                              hipStream_t stream)
{
    const float* x_order   = (const float*)d_in[0];
    const float* x_rider   = (const float*)d_in[1];
    const float* edge_attr = (const float*)d_in[2];
    const int*   order_idx = (const int*)d_in[3];
    const int*   rider_idx = (const int*)d_in[4];
    const float* omega     = (const float*)d_in[5];
    const float* Wk = (const float*)d_in[6];  const float* bk = (const float*)d_in[7];
    const float* Wq = (const float*)d_in[8];  const float* bq = (const float*)d_in[9];
    const float* Wv = (const float*)d_in[10]; const float* bv = (const float*)d_in[11];
    const float* We = (const float*)d_in[12];
    const float* Wskip = (const float*)d_in[13]; const float* bskip = (const float*)d_in[14];
    const float* Wp = (const float*)d_in[15]; const float* bp = (const float*)d_in[16];
    const float* W1 = (const float*)d_in[17]; const float* b1 = (const float*)d_in[18];
    const float* W2 = (const float*)d_in[19]; const float* b2 = (const float*)d_in[20];
    float* out = (float*)d_out;

    float* wsf     = (float*)d_ws;
    unsigned int* ws_kv = (unsigned int*)wsf;                 // NO*64 u32
    float* ws_p    = wsf + (size_t)NO_N * 64;                 // NO*64 f32
    float* ws_q    = ws_p + (size_t)NO_N * 64;
    float* ws_skip = ws_q + NR_N * 64;
    float* ws_emb  = ws_skip + NR_N * 64;
    float* ws_t    = ws_emb + NR_N * 64;
    float* ws_b1e  = ws_t + NR_N * 4;
    int* ws_counts  = (int*)(ws_b1e + 128);
    int* ws_offsets = ws_counts + NR_N;
    int* ws_cursor  = ws_offsets + NR_N + 8;
    int* ws_sorted  = ws_cursor + NR_N;

    hipMemsetAsync(ws_counts, 0, NR_N * sizeof(int), stream);

    k_prep_rider<<<NR_N / 4, 256, 0, stream>>>(x_rider, Wq, bq, Wskip, bskip, We,
                                               ws_q, ws_skip, ws_t);
    k_prep_b1eff<<<1, 128, 0, stream>>>(W1, b1, omega, ws_b1e);
    k_kvp<<<1024, 256, 0, stream>>>(x_order, Wk, bk, Wv, bv, Wp, bp, ws_kv, ws_p);
    k_hist<<<512, 256, 0, stream>>>(rider_idx, ws_counts);
    k_scan<<<1, 1024, 0, stream>>>(ws_counts, ws_offsets, ws_cursor);
    k_scatter<<<512, 256, 0, stream>>>(rider_idx, ws_cursor, ws_sorted);
    k_rider<<<NR_N, 1024, 0, stream>>>(ws_offsets, ws_sorted, order_idx, edge_attr,
                                       ws_q, ws_t, ws_kv, We, ws_skip, ws_emb);
    k_edge<<<1024, 256, 0, stream>>>(order_idx, rider_idx, ws_p, ws_emb,
                                     W1, ws_b1e, W2, b2, out);
}

// Round 3
// 451.268 us; speedup vs baseline: 3.2102x; 1.4468x over previous
//
#include <hip/hip_runtime.h>
#include <hip/hip_bf16.h>
#include <math.h>

#define NO_N 100000
#define NR_N 1000
#define E_N  1000000
#define SB     250      // scatter blocks
#define SCHUNK 4000     // edges per scatter block (SB*SCHUNK == E_N)

typedef short bf16x8 __attribute__((ext_vector_type(8)));
typedef float floatx4 __attribute__((ext_vector_type(4)));

__device__ __forceinline__ unsigned short bfu(float x) {
    union { __hip_bfloat16 h; unsigned short u; } c;
    c.h = __float2bfloat16(x);
    return c.u;
}

// ---------------------------------------------------------------------------
// prep: q[r,h], skip[r,h], t[r,d] = sum_h We[d,h]*q[r,h]
// ---------------------------------------------------------------------------
__global__ __launch_bounds__(256) void k_prep_rider(
    const float* __restrict__ xr,
    const float* __restrict__ Wq, const float* __restrict__ bq,
    const float* __restrict__ Wskip, const float* __restrict__ bskip,
    const float* __restrict__ We,
    float* __restrict__ q, float* __restrict__ skip, float* __restrict__ t)
{
    __shared__ float sx[4][32];
    __shared__ float sq[4][64];
    int tid = threadIdx.x;
    int rbase = blockIdx.x * 4;
    if (tid < 128) {
        int rl = tid >> 5, d = tid & 31;
        int r = rbase + rl;
        sx[rl][d] = (r < NR_N) ? xr[r * 32 + d] : 0.f;
    }
    __syncthreads();
    int rl = tid >> 6, h = tid & 63;
    int r = rbase + rl;
    float aq = bq[h], as = bskip[h];
    #pragma unroll 4
    for (int d = 0; d < 32; ++d) {
        float xv = sx[rl][d];
        aq += xv * Wq[d * 64 + h];
        as += xv * Wskip[d * 64 + h];
    }
    sq[rl][h] = aq;
    if (r < NR_N) { q[r * 64 + h] = aq; skip[r * 64 + h] = as; }
    __syncthreads();
    if (tid < 16) {
        int rl2 = tid >> 2, d = tid & 3;
        int r2 = rbase + rl2;
        float acc = 0.f;
        for (int hh = 0; hh < 64; ++hh) acc += We[d * 64 + hh] * sq[rl2][hh];
        if (r2 < NR_N) t[r2 * 4 + d] = acc;
    }
}

// b1eff[c] = b1[c] + sum_j omega[j] * W1[128+j][c]
__global__ __launch_bounds__(128) void k_prep_b1eff(
    const float* __restrict__ W1, const float* __restrict__ b1,
    const float* __restrict__ omega, float* __restrict__ b1eff)
{
    int c = threadIdx.x;
    float acc = b1[c];
    #pragma unroll 4
    for (int j = 0; j < 32; ++j) acc += omega[j] * W1[(128 + j) * 128 + c];
    b1eff[c] = acc;
}

// ---------------------------------------------------------------------------
// kv packed bf16 (k | v<<16) and p f32 = x_order @ {Wk,Wv,Wp} + bias
// ---------------------------------------------------------------------------
__global__ __launch_bounds__(256) void k_kvp(
    const float* __restrict__ x,
    const float* __restrict__ Wk, const float* __restrict__ bk,
    const float* __restrict__ Wv, const float* __restrict__ bv,
    const float* __restrict__ Wp, const float* __restrict__ bp,
    unsigned int* __restrict__ okv, float* __restrict__ op)
{
    __shared__ __align__(16) float sWk[4096];
    __shared__ __align__(16) float sWv[4096];
    __shared__ __align__(16) float sWp[4096];
    __shared__ float sx[4][64];
    int tid = threadIdx.x;
    {
        const float4* a = (const float4*)Wk;
        const float4* b = (const float4*)Wv;
        const float4* c = (const float4*)Wp;
        float4* A = (float4*)sWk; float4* B = (float4*)sWv; float4* C = (float4*)sWp;
        for (int i = tid; i < 1024; i += 256) { A[i] = a[i]; B[i] = b[i]; C[i] = c[i]; }
    }
    __syncthreads();
    int wave = tid >> 6, lane = tid & 63;
    float bkl = bk[lane], bvl = bv[lane], bpl = bp[lane];
    int gw = blockIdx.x * 4 + wave;
    int stride = gridDim.x * 4;
    for (int row = gw; row < NO_N; row += stride) {
        sx[wave][lane] = x[(size_t)row * 64 + lane];
        float ak = bkl, av = bvl, ap = bpl;
        #pragma unroll 8
        for (int d = 0; d < 64; ++d) {
            float xd = sx[wave][d];
            ak = fmaf(xd, sWk[d * 64 + lane], ak);
            av = fmaf(xd, sWv[d * 64 + lane], av);
            ap = fmaf(xd, sWp[d * 64 + lane], ap);
        }
        size_t o = (size_t)row * 64 + lane;
        okv[o] = (unsigned int)bfu(ak) | ((unsigned int)bfu(av) << 16);
        op[o] = ap;
    }
}

// ---------------------------------------------------------------------------
// CSR build, atomic-free version:
//  k_hist2:  per-block LDS histogram -> plain stores ghist[r*SB + b]
//  k_colscan: per-rider prefix over blocks -> gpre[r*SB+b], counts[r]
//  k_scan:   exclusive scan over riders -> offsets[r]
//  k_scatter2: LDS cursors = offsets[r]+gpre[r][b]; LDS-atomic rank; plain store
// ---------------------------------------------------------------------------
__global__ __launch_bounds__(256) void k_hist2(const int* __restrict__ ridx,
                                               int* __restrict__ ghist)
{
    __shared__ int hc[NR_N];
    int tid = threadIdx.x, b = blockIdx.x;
    for (int i = tid; i < NR_N; i += 256) hc[i] = 0;
    __syncthreads();
    int s = b * SCHUNK;
    for (int i = s + tid; i < s + SCHUNK; i += 256)
        atomicAdd(&hc[ridx[i]], 1);
    __syncthreads();
    for (int i = tid; i < NR_N; i += 256)
        ghist[i * SB + b] = hc[i];
}

__global__ __launch_bounds__(256) void k_colscan(const int* __restrict__ ghist,
                                                 int* __restrict__ gpre,
                                                 int* __restrict__ counts)
{
    __shared__ int s[256];
    int tid = threadIdx.x, r = blockIdx.x;
    int v = (tid < SB) ? ghist[r * SB + tid] : 0;
    s[tid] = v;
    __syncthreads();
    for (int off = 1; off < 256; off <<= 1) {
        int tv = (tid >= off) ? s[tid - off] : 0;
        __syncthreads();
        s[tid] += tv;
        __syncthreads();
    }
    if (tid < SB) gpre[r * SB + tid] = s[tid] - v;   // exclusive over blocks
    if (tid == 255) counts[r] = s[255];
}

__global__ __launch_bounds__(1024) void k_scan(const int* __restrict__ counts,
                                               int* __restrict__ offsets)
{
    __shared__ int s[1024];
    int tid = threadIdx.x;
    int c = (tid < NR_N) ? counts[tid] : 0;
    s[tid] = c;
    __syncthreads();
    for (int off = 1; off < 1024; off <<= 1) {
        int tv = (tid >= off) ? s[tid - off] : 0;
        __syncthreads();
        s[tid] += tv;
        __syncthreads();
    }
    if (tid < NR_N) offsets[tid] = s[tid] - c;
    if (tid == NR_N - 1) offsets[NR_N] = s[tid];
}

__global__ __launch_bounds__(256) void k_scatter2(const int* __restrict__ ridx,
                                                  const int* __restrict__ offsets,
                                                  const int* __restrict__ gpre,
                                                  int* __restrict__ sorted)
{
    __shared__ int cur[NR_N];
    int tid = threadIdx.x, b = blockIdx.x;
    for (int i = tid; i < NR_N; i += 256)
        cur[i] = offsets[i] + gpre[i * SB + b];
    __syncthreads();
    int s = b * SCHUNK;
    for (int i = s + tid; i < s + SCHUNK; i += 256) {
        int pos = atomicAdd(&cur[ridx[i]], 1);     // LDS atomic only
        sorted[pos] = i;
    }
}

// ---------------------------------------------------------------------------
// rider embedding. Waves take contiguous edge chunks; 64 edge indices are
// batch-loaded then broadcast by __shfl. kv gathered as packed bf16 pairs.
// ---------------------------------------------------------------------------
__global__ __launch_bounds__(1024) void k_rider(
    const int* __restrict__ offsets, const int* __restrict__ sorted,
    const int* __restrict__ oidx, const float* __restrict__ ea,
    const float* __restrict__ q, const float* __restrict__ t,
    const unsigned int* __restrict__ kv,
    const float* __restrict__ We, const float* __restrict__ skip,
    float* __restrict__ emb)
{
    int r = blockIdx.x;
    int wave = threadIdx.x >> 6, lane = threadIdx.x & 63;
    int beg = offsets[r], end = offsets[r + 1];
    int cnt = end - beg;
    int chunk = (cnt + 15) >> 4;
    int s0 = beg + wave * chunk;
    int s1 = min(s0 + chunk, end);

    float ql = q[r * 64 + lane];
    float t0 = t[r * 4 + 0], t1 = t[r * 4 + 1], t2 = t[r * 4 + 2], t3 = t[r * 4 + 3];

    float aggv = 0.f, dsum = 0.f;
    float ag0 = 0.f, ag1 = 0.f, ag2 = 0.f, ag3 = 0.f;

    for (int jb = s0; jb < s1; jb += 64) {
        int j = jb + lane;
        bool valid = (j < s1);
        int ee = valid ? sorted[j] : 0;
        int oo = valid ? oidx[ee] : 0;
        float4 eav = make_float4(0.f, 0.f, 0.f, 0.f);
        if (valid) eav = *(const float4*)(ea + (size_t)ee * 4);
        float ealpha = eav.x * t0 + eav.y * t1 + eav.z * t2 + eav.w * t3;
        int nn = min(s1 - jb, 64);
        for (int i = 0; i < nn; ++i) {
            int o = __shfl(oo, i);
            unsigned int u = kv[(size_t)o * 64 + lane];
            float kl = __uint_as_float(u << 16);
            float vl = __uint_as_float(u & 0xffff0000u);
            float c = ql * kl;
            #pragma unroll
            for (int m = 1; m < 64; m <<= 1) c += __shfl_xor(c, m);
            c += __shfl(ealpha, i);
            float exv = __expf(c * 0.125f);
            dsum += exv;
            aggv = fmaf(exv, vl, aggv);
            float msk = (lane == i) ? exv : 0.f;
            ag0 = fmaf(msk, eav.x, ag0);
            ag1 = fmaf(msk, eav.y, ag1);
            ag2 = fmaf(msk, eav.z, ag2);
            ag3 = fmaf(msk, eav.w, ag3);
        }
    }
    #pragma unroll
    for (int m = 1; m < 64; m <<= 1) {
        ag0 += __shfl_xor(ag0, m);
        ag1 += __shfl_xor(ag1, m);
        ag2 += __shfl_xor(ag2, m);
        ag3 += __shfl_xor(ag3, m);
    }

    __shared__ float rv[16][64];
    __shared__ float re4[16][4];
    __shared__ float rd[16];
    rv[wave][lane] = aggv;
    if (lane == 0) {
        rd[wave] = dsum;
        re4[wave][0] = ag0; re4[wave][1] = ag1;
        re4[wave][2] = ag2; re4[wave][3] = ag3;
    }
    __syncthreads();
    if (threadIdx.x < 64) {
        int l = threadIdx.x;
        float av = 0.f, ds = 0.f, a0 = 0.f, a1 = 0.f, a2 = 0.f, a3 = 0.f;
        #pragma unroll 4
        for (int w = 0; w < 16; ++w) {
            av += rv[w][l]; ds += rd[w];
            a0 += re4[w][0]; a1 += re4[w][1]; a2 += re4[w][2]; a3 += re4[w][3];
        }
        float corr = a0 * We[0 * 64 + l] + a1 * We[1 * 64 + l]
                   + a2 * We[2 * 64 + l] + a3 * We[3 * 64 + l];
        emb[r * 64 + l] = (av + corr) / (ds + 1e-16f) + skip[r * 64 + l];
    }
}

// ---------------------------------------------------------------------------
// per-edge scoring via bf16 MFMA (W1 persistent in register fragments).
// ---------------------------------------------------------------------------
__global__ __launch_bounds__(256, 4) void k_edge(
    const int* __restrict__ oidx, const int* __restrict__ ridx,
    const float* __restrict__ p, const float* __restrict__ emb,
    const float* __restrict__ W1, const float* __restrict__ b1eff,
    const float* __restrict__ W2, const float* __restrict__ b2,
    float* __restrict__ out)
{
    __shared__ __align__(16) unsigned short sA[64 * 136];
    __shared__ float sDot[64];
    __shared__ float sPart[4][64];

    const int tid = threadIdx.x;
    const int wave = tid >> 6;
    const int lane = tid & 63;
    const int l15 = lane & 15;
    const int quad = lane >> 4;

    bf16x8 bfr[2][4];
    float b1v[2], w2v[2];
    #pragma unroll
    for (int ctl = 0; ctl < 2; ++ctl) {
        int n = wave * 32 + ctl * 16 + l15;
        b1v[ctl] = b1eff[n];
        w2v[ctl] = W2[n];
        #pragma unroll
        for (int kc = 0; kc < 4; ++kc) {
            int k0 = kc * 32 + quad * 8;
            bf16x8 f;
            #pragma unroll
            for (int j = 0; j < 8; ++j)
                f[j] = (short)bfu(W1[(size_t)(k0 + j) * 128 + n]);
            bfr[ctl][kc] = f;
        }
    }
    float b2v = b2[0];

    const int el = tid >> 2;
    const int qd = (tid & 3) * 16;

    for (int tile = blockIdx.x; tile < E_N / 64; tile += gridDim.x) {
        int ebase = tile * 64;
        {
            int e = ebase + el;
            int o = oidx[e];
            int r = ridx[e];
            const float4* po = (const float4*)(p + (size_t)o * 64 + qd);
            const float4* pr = (const float4*)(emb + (size_t)r * 64 + qd);
            unsigned short* rowA = sA + el * 136;
            float dotp = 0.f;
            #pragma unroll
            for (int i = 0; i < 4; ++i) {
                float4 a = po[i];
                float4 b = pr[i];
                dotp += a.x * b.x + a.y * b.y + a.z * b.z + a.w * b.w;
                ushort4 ua = { bfu(a.x), bfu(a.y), bfu(a.z), bfu(a.w) };
                ushort4 ub = { bfu(b.x), bfu(b.y), bfu(b.z), bfu(b.w) };
                *(ushort4*)(rowA + qd + i * 4) = ua;
                *(ushort4*)(rowA + 64 + qd + i * 4) = ub;
            }
            dotp += __shfl_xor(dotp, 1);
            dotp += __shfl_xor(dotp, 2);
            if ((tid & 3) == 0) sDot[el] = dotp;
        }
        __syncthreads();

        floatx4 acc[4][2];
        #pragma unroll
        for (int rt = 0; rt < 4; ++rt)
            #pragma unroll
            for (int ctl = 0; ctl < 2; ++ctl)
                acc[rt][ctl] = (floatx4){0.f, 0.f, 0.f, 0.f};

        #pragma unroll
        for (int rt = 0; rt < 4; ++rt) {
            const unsigned short* ar = sA + (size_t)(rt * 16 + l15) * 136 + quad * 8;
            bf16x8 a0 = *(const bf16x8*)(ar);
            bf16x8 a1 = *(const bf16x8*)(ar + 32);
            bf16x8 a2 = *(const bf16x8*)(ar + 64);
            bf16x8 a3 = *(const bf16x8*)(ar + 96);
            #pragma unroll
            for (int ctl = 0; ctl < 2; ++ctl) {
                floatx4 c = acc[rt][ctl];
                c = __builtin_amdgcn_mfma_f32_16x16x32_bf16(a0, bfr[ctl][0], c, 0, 0, 0);
                c = __builtin_amdgcn_mfma_f32_16x16x32_bf16(a1, bfr[ctl][1], c, 0, 0, 0);
                c = __builtin_amdgcn_mfma_f32_16x16x32_bf16(a2, bfr[ctl][2], c, 0, 0, 0);
                c = __builtin_amdgcn_mfma_f32_16x16x32_bf16(a3, bfr[ctl][3], c, 0, 0, 0);
                acc[rt][ctl] = c;
            }
        }

        #pragma unroll
        for (int rt = 0; rt < 4; ++rt) {
            floatx4 s;
            #pragma unroll
            for (int g = 0; g < 4; ++g)
                s[g] = fmaxf(acc[rt][0][g] + b1v[0], 0.f) * w2v[0]
                     + fmaxf(acc[rt][1][g] + b1v[1], 0.f) * w2v[1];
            #pragma unroll
            for (int m = 1; m < 16; m <<= 1) {
                s[0] += __shfl_xor(s[0], m);
                s[1] += __shfl_xor(s[1], m);
                s[2] += __shfl_xor(s[2], m);
                s[3] += __shfl_xor(s[3], m);
            }
            if (l15 == 0) {
                int rowb = rt * 16 + quad * 4;
                sPart[wave][rowb + 0] = s[0];
                sPart[wave][rowb + 1] = s[1];
                sPart[wave][rowb + 2] = s[2];
                sPart[wave][rowb + 3] = s[3];
            }
        }
        __syncthreads();
        if (tid < 64) {
            float v = sPart[0][tid] + sPart[1][tid] + sPart[2][tid] + sPart[3][tid]
                    + 0.125f * sDot[tid] + b2v;
            out[ebase + tid] = fminf(fmaxf(v, -10.f), 10.f);
        }
        __syncthreads();
    }
}

// ---------------------------------------------------------------------------
extern "C" void kernel_launch(void* const* d_in, const int* in_sizes, int n_in,
                              void* d_out, int out_size, void* d_ws, size_t ws_size,
                              hipStream_t stream)
{
    const float* x_order   = (const float*)d_in[0];
    const float* x_rider   = (const float*)d_in[1];
    const float* edge_attr = (const float*)d_in[2];
    const int*   order_idx = (const int*)d_in[3];
    const int*   rider_idx = (const int*)d_in[4];
    const float* omega     = (const float*)d_in[5];
    const float* Wk = (const float*)d_in[6];  const float* bk = (const float*)d_in[7];
    const float* Wq = (const float*)d_in[8];  const float* bq = (const float*)d_in[9];
    const float* Wv = (const float*)d_in[10]; const float* bv = (const float*)d_in[11];
    const float* We = (const float*)d_in[12];
    const float* Wskip = (const float*)d_in[13]; const float* bskip = (const float*)d_in[14];
    const float* Wp = (const float*)d_in[15]; const float* bp = (const float*)d_in[16];
    const float* W1 = (const float*)d_in[17]; const float* b1 = (const float*)d_in[18];
    const float* W2 = (const float*)d_in[19]; const float* b2 = (const float*)d_in[20];
    float* out = (float*)d_out;

    float* wsf     = (float*)d_ws;
    unsigned int* ws_kv = (unsigned int*)wsf;                 // NO*64 u32
    float* ws_p    = wsf + (size_t)NO_N * 64;                 // NO*64 f32
    float* ws_q    = ws_p + (size_t)NO_N * 64;
    float* ws_skip = ws_q + NR_N * 64;
    float* ws_emb  = ws_skip + NR_N * 64;
    float* ws_t    = ws_emb + NR_N * 64;
    float* ws_b1e  = ws_t + NR_N * 4;
    int* ws_counts  = (int*)(ws_b1e + 128);
    int* ws_offsets = ws_counts + NR_N;
    int* ws_sorted  = ws_offsets + NR_N + 8;
    int* ws_ghist   = ws_sorted + E_N;
    int* ws_gpre    = ws_ghist + NR_N * SB;

    k_prep_rider<<<NR_N / 4, 256, 0, stream>>>(x_rider, Wq, bq, Wskip, bskip, We,
                                               ws_q, ws_skip, ws_t);
    k_prep_b1eff<<<1, 128, 0, stream>>>(W1, b1, omega, ws_b1e);
    k_kvp<<<1024, 256, 0, stream>>>(x_order, Wk, bk, Wv, bv, Wp, bp, ws_kv, ws_p);
    k_hist2<<<SB, 256, 0, stream>>>(rider_idx, ws_ghist);
    k_colscan<<<NR_N, 256, 0, stream>>>(ws_ghist, ws_gpre, ws_counts);
    k_scan<<<1, 1024, 0, stream>>>(ws_counts, ws_offsets);
    k_scatter2<<<SB, 256, 0, stream>>>(rider_idx, ws_offsets, ws_gpre, ws_sorted);
    k_rider<<<NR_N, 1024, 0, stream>>>(ws_offsets, ws_sorted, order_idx, edge_attr,
                                       ws_q, ws_t, ws_kv, We, ws_skip, ws_emb);
    k_edge<<<1024, 256, 0, stream>>>(order_idx, rider_idx, ws_p, ws_emb,
                                     W1, ws_b1e, W2, b2, out);
}

// Round 4
// 393.897 us; speedup vs baseline: 3.6778x; 1.1456x over previous
//
#include <hip/hip_runtime.h>
#include <hip/hip_bf16.h>
#include <math.h>

#define NO_N 100000
#define NR_N 1000
#define E_N  1000000
#define SB     250      // scatter blocks
#define SCHUNK 4000     // edges per scatter block (SB*SCHUNK == E_N)

typedef short bf16x8 __attribute__((ext_vector_type(8)));
typedef float floatx4 __attribute__((ext_vector_type(4)));

__device__ __forceinline__ unsigned short bfu(float x) {
    union { __hip_bfloat16 h; unsigned short u; } c;
    c.h = __float2bfloat16(x);
    return c.u;
}
__device__ __forceinline__ float bflo(unsigned int u) {      // low u16 -> f32
    return __uint_as_float(u << 16);
}
__device__ __forceinline__ float bfhi(unsigned int u) {      // high u16 -> f32
    return __uint_as_float(u & 0xffff0000u);
}

// ---------------------------------------------------------------------------
// prep: q[r,h], skip[r,h], t[r,d] = sum_h We[d,h]*q[r,h]
// ---------------------------------------------------------------------------
__global__ __launch_bounds__(256) void k_prep_rider(
    const float* __restrict__ xr,
    const float* __restrict__ Wq, const float* __restrict__ bq,
    const float* __restrict__ Wskip, const float* __restrict__ bskip,
    const float* __restrict__ We,
    float* __restrict__ q, float* __restrict__ skip, float* __restrict__ t)
{
    __shared__ float sx[4][32];
    __shared__ float sq[4][64];
    int tid = threadIdx.x;
    int rbase = blockIdx.x * 4;
    if (tid < 128) {
        int rl = tid >> 5, d = tid & 31;
        int r = rbase + rl;
        sx[rl][d] = (r < NR_N) ? xr[r * 32 + d] : 0.f;
    }
    __syncthreads();
    int rl = tid >> 6, h = tid & 63;
    int r = rbase + rl;
    float aq = bq[h], as = bskip[h];
    #pragma unroll 4
    for (int d = 0; d < 32; ++d) {
        float xv = sx[rl][d];
        aq += xv * Wq[d * 64 + h];
        as += xv * Wskip[d * 64 + h];
    }
    sq[rl][h] = aq;
    if (r < NR_N) { q[r * 64 + h] = aq; skip[r * 64 + h] = as; }
    __syncthreads();
    if (tid < 16) {
        int rl2 = tid >> 2, d = tid & 3;
        int r2 = rbase + rl2;
        float acc = 0.f;
        for (int hh = 0; hh < 64; ++hh) acc += We[d * 64 + hh] * sq[rl2][hh];
        if (r2 < NR_N) t[r2 * 4 + d] = acc;
    }
}

// b1eff[c] = b1[c] + sum_j omega[j] * W1[128+j][c]
__global__ __launch_bounds__(128) void k_prep_b1eff(
    const float* __restrict__ W1, const float* __restrict__ b1,
    const float* __restrict__ omega, float* __restrict__ b1eff)
{
    int c = threadIdx.x;
    float acc = b1[c];
    #pragma unroll 4
    for (int j = 0; j < 32; ++j) acc += omega[j] * W1[(128 + j) * 128 + c];
    b1eff[c] = acc;
}

// ---------------------------------------------------------------------------
// kb,vb,pb (bf16 tables) = x_order @ {Wk,Wv,Wp} + bias
// ---------------------------------------------------------------------------
__global__ __launch_bounds__(256) void k_kvp(
    const float* __restrict__ x,
    const float* __restrict__ Wk, const float* __restrict__ bk,
    const float* __restrict__ Wv, const float* __restrict__ bv,
    const float* __restrict__ Wp, const float* __restrict__ bp,
    unsigned short* __restrict__ kb, unsigned short* __restrict__ vb,
    unsigned short* __restrict__ pb)
{
    __shared__ __align__(16) float sWk[4096];
    __shared__ __align__(16) float sWv[4096];
    __shared__ __align__(16) float sWp[4096];
    __shared__ float sx[4][64];
    int tid = threadIdx.x;
    {
        const float4* a = (const float4*)Wk;
        const float4* b = (const float4*)Wv;
        const float4* c = (const float4*)Wp;
        float4* A = (float4*)sWk; float4* B = (float4*)sWv; float4* C = (float4*)sWp;
        for (int i = tid; i < 1024; i += 256) { A[i] = a[i]; B[i] = b[i]; C[i] = c[i]; }
    }
    __syncthreads();
    int wave = tid >> 6, lane = tid & 63;
    float bkl = bk[lane], bvl = bv[lane], bpl = bp[lane];
    int gw = blockIdx.x * 4 + wave;
    int stride = gridDim.x * 4;
    for (int row = gw; row < NO_N; row += stride) {
        sx[wave][lane] = x[(size_t)row * 64 + lane];
        float ak = bkl, av = bvl, ap = bpl;
        #pragma unroll 8
        for (int d = 0; d < 64; ++d) {
            float xd = sx[wave][d];
            ak = fmaf(xd, sWk[d * 64 + lane], ak);
            av = fmaf(xd, sWv[d * 64 + lane], av);
            ap = fmaf(xd, sWp[d * 64 + lane], ap);
        }
        size_t o = (size_t)row * 64 + lane;
        kb[o] = bfu(ak);
        vb[o] = bfu(av);
        pb[o] = bfu(ap);
    }
}

// ---------------------------------------------------------------------------
// CSR build (atomic-free across blocks):
//  k_hist2 -> ghist[r][b]; k_colscan -> gpre + counts; k_scan -> offsets;
//  k_scatter2: LDS cursors, packs per-edge record {o, h=ea.t, ea(bf16x4)}.
// ---------------------------------------------------------------------------
__global__ __launch_bounds__(256) void k_hist2(const int* __restrict__ ridx,
                                               int* __restrict__ ghist)
{
    __shared__ int hc[NR_N];
    int tid = threadIdx.x, b = blockIdx.x;
    for (int i = tid; i < NR_N; i += 256) hc[i] = 0;
    __syncthreads();
    int s = b * SCHUNK;
    for (int i = s + tid; i < s + SCHUNK; i += 256)
        atomicAdd(&hc[ridx[i]], 1);
    __syncthreads();
    for (int i = tid; i < NR_N; i += 256)
        ghist[i * SB + b] = hc[i];
}

__global__ __launch_bounds__(256) void k_colscan(const int* __restrict__ ghist,
                                                 int* __restrict__ gpre,
                                                 int* __restrict__ counts)
{
    __shared__ int s[256];
    int tid = threadIdx.x, r = blockIdx.x;
    int v = (tid < SB) ? ghist[r * SB + tid] : 0;
    s[tid] = v;
    __syncthreads();
    for (int off = 1; off < 256; off <<= 1) {
        int tv = (tid >= off) ? s[tid - off] : 0;
        __syncthreads();
        s[tid] += tv;
        __syncthreads();
    }
    if (tid < SB) gpre[r * SB + tid] = s[tid] - v;
    if (tid == 255) counts[r] = s[255];
}

__global__ __launch_bounds__(1024) void k_scan(const int* __restrict__ counts,
                                               int* __restrict__ offsets)
{
    __shared__ int s[1024];
    int tid = threadIdx.x;
    int c = (tid < NR_N) ? counts[tid] : 0;
    s[tid] = c;
    __syncthreads();
    for (int off = 1; off < 1024; off <<= 1) {
        int tv = (tid >= off) ? s[tid - off] : 0;
        __syncthreads();
        s[tid] += tv;
        __syncthreads();
    }
    if (tid < NR_N) offsets[tid] = s[tid] - c;
    if (tid == NR_N - 1) offsets[NR_N] = s[tid];
}

__global__ __launch_bounds__(256) void k_scatter2(
    const int* __restrict__ ridx, const int* __restrict__ oidx,
    const float* __restrict__ ea, const float* __restrict__ t,
    const int* __restrict__ offsets, const int* __restrict__ gpre,
    int4* __restrict__ spack)
{
    __shared__ int cur[NR_N];
    int tid = threadIdx.x, b = blockIdx.x;
    for (int i = tid; i < NR_N; i += 256)
        cur[i] = offsets[i] + gpre[i * SB + b];
    __syncthreads();
    int s = b * SCHUNK;
    for (int i = s + tid; i < s + SCHUNK; i += 256) {
        int r = ridx[i];
        float4 e4 = *(const float4*)(ea + (size_t)i * 4);
        float4 t4 = *(const float4*)(t + r * 4);
        float h = e4.x * t4.x + e4.y * t4.y + e4.z * t4.z + e4.w * t4.w;
        int pos = atomicAdd(&cur[r], 1);     // LDS atomic only
        int4 pk;
        pk.x = oidx[i];
        pk.y = __float_as_int(h);
        pk.z = (int)((unsigned)bfu(e4.x) | ((unsigned)bfu(e4.y) << 16));
        pk.w = (int)((unsigned)bfu(e4.z) | ((unsigned)bfu(e4.w) << 16));
        spack[pos] = pk;
    }
}

// ---------------------------------------------------------------------------
// rider embedding, restructured for memory-level parallelism:
// phase A (lane-per-edge): k-row via 8 independent dwordx4, dot vs q (LDS
//   broadcast), alpha = (q.k + h)*0.125, exv per lane. No shuffle reduce.
// phase B (dim-per-lane): {o,exv} via LDS pairs, vb rows gathered in groups
//   of 8 independent loads.
// ---------------------------------------------------------------------------
__global__ __launch_bounds__(1024) void k_rider(
    const int* __restrict__ offsets, const int4* __restrict__ spack,
    const float* __restrict__ q,
    const unsigned short* __restrict__ kb, const unsigned short* __restrict__ vb,
    const float* __restrict__ We, const float* __restrict__ skip,
    float* __restrict__ emb)
{
    __shared__ float sQ[64];
    __shared__ int2 sOX[16][64];
    __shared__ float rv[16][64];
    __shared__ float re4[16][4];
    __shared__ float rd[16];

    int r = blockIdx.x;
    int wave = threadIdx.x >> 6, lane = threadIdx.x & 63;
    if (threadIdx.x < 64) sQ[threadIdx.x] = q[r * 64 + threadIdx.x];
    __syncthreads();

    int beg = offsets[r], end = offsets[r + 1];
    int cnt = end - beg;
    int chunk = (cnt + 15) >> 4;
    int s0 = beg + wave * chunk;
    int s1 = min(s0 + chunk, end);

    float aggv = 0.f, dsum = 0.f;
    float ag0 = 0.f, ag1 = 0.f, ag2 = 0.f, ag3 = 0.f;
    const float2* sQ2 = (const float2*)sQ;

    for (int jb = s0; jb < s1; jb += 64) {
        int j = jb + lane;
        bool valid = (j < s1);
        int4 pk = make_int4(0, 0, 0, 0);
        if (valid) pk = spack[j];
        int oo = pk.x;
        float h = __int_as_float(pk.y);

        // ---- phase A: own-edge q.k dot (8 independent 16B loads) ----
        const uint4* krow = (const uint4*)(kb + (size_t)oo * 64);
        uint4 K0 = krow[0], K1 = krow[1], K2 = krow[2], K3 = krow[3];
        uint4 K4 = krow[4], K5 = krow[5], K6 = krow[6], K7 = krow[7];
        float acc = h;
        #define DOT8(Kv, base) { \
            float2 qa = sQ2[(base) + 0]; \
            acc = fmaf(bflo(Kv.x), qa.x, acc); acc = fmaf(bfhi(Kv.x), qa.y, acc); \
            float2 qb = sQ2[(base) + 1]; \
            acc = fmaf(bflo(Kv.y), qb.x, acc); acc = fmaf(bfhi(Kv.y), qb.y, acc); \
            float2 qc = sQ2[(base) + 2]; \
            acc = fmaf(bflo(Kv.z), qc.x, acc); acc = fmaf(bfhi(Kv.z), qc.y, acc); \
            float2 qd = sQ2[(base) + 3]; \
            acc = fmaf(bflo(Kv.w), qd.x, acc); acc = fmaf(bfhi(Kv.w), qd.y, acc); }
        DOT8(K0, 0) DOT8(K1, 4) DOT8(K2, 8) DOT8(K3, 12)
        DOT8(K4, 16) DOT8(K5, 20) DOT8(K6, 24) DOT8(K7, 28)
        #undef DOT8

        float exv = valid ? __expf(acc * 0.125f) : 0.f;
        dsum += exv;
        unsigned int ez = (unsigned int)pk.z, ew = (unsigned int)pk.w;
        ag0 = fmaf(exv, bflo(ez), ag0);
        ag1 = fmaf(exv, bfhi(ez), ag1);
        ag2 = fmaf(exv, bflo(ew), ag2);
        ag3 = fmaf(exv, bfhi(ew), ag3);

        sOX[wave][lane] = make_int2(oo, __float_as_int(exv));

        // ---- phase B: dim-per-lane aggregation of v ----
        int nn = min(s1 - jb, 64);
        int i = 0;
        for (; i + 8 <= nn; i += 8) {
            int2 x0 = sOX[wave][i + 0], x1 = sOX[wave][i + 1];
            int2 x2 = sOX[wave][i + 2], x3 = sOX[wave][i + 3];
            int2 x4 = sOX[wave][i + 4], x5 = sOX[wave][i + 5];
            int2 x6 = sOX[wave][i + 6], x7 = sOX[wave][i + 7];
            unsigned short u0 = vb[(size_t)x0.x * 64 + lane];
            unsigned short u1 = vb[(size_t)x1.x * 64 + lane];
            unsigned short u2 = vb[(size_t)x2.x * 64 + lane];
            unsigned short u3 = vb[(size_t)x3.x * 64 + lane];
            unsigned short u4 = vb[(size_t)x4.x * 64 + lane];
            unsigned short u5 = vb[(size_t)x5.x * 64 + lane];
            unsigned short u6 = vb[(size_t)x6.x * 64 + lane];
            unsigned short u7 = vb[(size_t)x7.x * 64 + lane];
            aggv = fmaf(__int_as_float(x0.y), bflo((unsigned int)u0 << 0) , aggv);
            aggv = fmaf(__int_as_float(x1.y), __uint_as_float((unsigned int)u1 << 16), aggv);
            aggv = fmaf(__int_as_float(x2.y), __uint_as_float((unsigned int)u2 << 16), aggv);
            aggv = fmaf(__int_as_float(x3.y), __uint_as_float((unsigned int)u3 << 16), aggv);
            aggv = fmaf(__int_as_float(x4.y), __uint_as_float((unsigned int)u4 << 16), aggv);
            aggv = fmaf(__int_as_float(x5.y), __uint_as_float((unsigned int)u5 << 16), aggv);
            aggv = fmaf(__int_as_float(x6.y), __uint_as_float((unsigned int)u6 << 16), aggv);
            aggv = fmaf(__int_as_float(x7.y), __uint_as_float((unsigned int)u7 << 16), aggv);
        }
        for (; i < nn; ++i) {
            int2 xx = sOX[wave][i];
            unsigned short uu = vb[(size_t)xx.x * 64 + lane];
            aggv = fmaf(__int_as_float(xx.y), __uint_as_float((unsigned int)uu << 16), aggv);
        }
    }

    #pragma unroll
    for (int m = 1; m < 64; m <<= 1) {
        dsum += __shfl_xor(dsum, m);
        ag0 += __shfl_xor(ag0, m);
        ag1 += __shfl_xor(ag1, m);
        ag2 += __shfl_xor(ag2, m);
        ag3 += __shfl_xor(ag3, m);
    }

    rv[wave][lane] = aggv;
    if (lane == 0) {
        rd[wave] = dsum;
        re4[wave][0] = ag0; re4[wave][1] = ag1;
        re4[wave][2] = ag2; re4[wave][3] = ag3;
    }
    __syncthreads();
    if (threadIdx.x < 64) {
        int l = threadIdx.x;
        float av = 0.f, ds = 0.f, a0 = 0.f, a1 = 0.f, a2 = 0.f, a3 = 0.f;
        #pragma unroll 4
        for (int w = 0; w < 16; ++w) {
            av += rv[w][l]; ds += rd[w];
            a0 += re4[w][0]; a1 += re4[w][1]; a2 += re4[w][2]; a3 += re4[w][3];
        }
        float corr = a0 * We[0 * 64 + l] + a1 * We[1 * 64 + l]
                   + a2 * We[2 * 64 + l] + a3 * We[3 * 64 + l];
        emb[r * 64 + l] = (av + corr) / (ds + 1e-16f) + skip[r * 64 + l];
    }
}

// ---------------------------------------------------------------------------
// per-edge scoring via bf16 MFMA (W1 persistent in register fragments).
// pb is bf16: staged bits go straight into the A tile; dot unpacks to f32.
// ---------------------------------------------------------------------------
__global__ __launch_bounds__(256, 4) void k_edge(
    const int* __restrict__ oidx, const int* __restrict__ ridx,
    const unsigned short* __restrict__ pb, const float* __restrict__ emb,
    const float* __restrict__ W1, const float* __restrict__ b1eff,
    const float* __restrict__ W2, const float* __restrict__ b2,
    float* __restrict__ out)
{
    __shared__ __align__(16) unsigned short sA[64 * 136];
    __shared__ float sDot[64];
    __shared__ float sPart[4][64];

    const int tid = threadIdx.x;
    const int wave = tid >> 6;
    const int lane = tid & 63;
    const int l15 = lane & 15;
    const int quad = lane >> 4;

    bf16x8 bfr[2][4];
    float b1v[2], w2v[2];
    #pragma unroll
    for (int ctl = 0; ctl < 2; ++ctl) {
        int n = wave * 32 + ctl * 16 + l15;
        b1v[ctl] = b1eff[n];
        w2v[ctl] = W2[n];
        #pragma unroll
        for (int kc = 0; kc < 4; ++kc) {
            int k0 = kc * 32 + quad * 8;
            bf16x8 f;
            #pragma unroll
            for (int j = 0; j < 8; ++j)
                f[j] = (short)bfu(W1[(size_t)(k0 + j) * 128 + n]);
            bfr[ctl][kc] = f;
        }
    }
    float b2v = b2[0];

    const int el = tid >> 2;
    const int qd = (tid & 3) * 16;

    for (int tile = blockIdx.x; tile < E_N / 64; tile += gridDim.x) {
        int ebase = tile * 64;
        {
            int e = ebase + el;
            int o = oidx[e];
            int r = ridx[e];
            const uint2* po = (const uint2*)(pb + (size_t)o * 64 + qd);
            const float4* pr = (const float4*)(emb + (size_t)r * 64 + qd);
            unsigned short* rowA = sA + el * 136;
            float dotp = 0.f;
            #pragma unroll
            for (int i = 0; i < 4; ++i) {
                uint2 a = po[i];
                float4 b = pr[i];
                dotp += bflo(a.x) * b.x + bfhi(a.x) * b.y
                      + bflo(a.y) * b.z + bfhi(a.y) * b.w;
                *(uint2*)(rowA + qd + i * 4) = a;
                ushort4 ub = { bfu(b.x), bfu(b.y), bfu(b.z), bfu(b.w) };
                *(ushort4*)(rowA + 64 + qd + i * 4) = ub;
            }
            dotp += __shfl_xor(dotp, 1);
            dotp += __shfl_xor(dotp, 2);
            if ((tid & 3) == 0) sDot[el] = dotp;
        }
        __syncthreads();

        floatx4 acc[4][2];
        #pragma unroll
        for (int rt = 0; rt < 4; ++rt)
            #pragma unroll
            for (int ctl = 0; ctl < 2; ++ctl)
                acc[rt][ctl] = (floatx4){0.f, 0.f, 0.f, 0.f};

        #pragma unroll
        for (int rt = 0; rt < 4; ++rt) {
            const unsigned short* ar = sA + (size_t)(rt * 16 + l15) * 136 + quad * 8;
            bf16x8 a0 = *(const bf16x8*)(ar);
            bf16x8 a1 = *(const bf16x8*)(ar + 32);
            bf16x8 a2 = *(const bf16x8*)(ar + 64);
            bf16x8 a3 = *(const bf16x8*)(ar + 96);
            #pragma unroll
            for (int ctl = 0; ctl < 2; ++ctl) {
                floatx4 c = acc[rt][ctl];
                c = __builtin_amdgcn_mfma_f32_16x16x32_bf16(a0, bfr[ctl][0], c, 0, 0, 0);
                c = __builtin_amdgcn_mfma_f32_16x16x32_bf16(a1, bfr[ctl][1], c, 0, 0, 0);
                c = __builtin_amdgcn_mfma_f32_16x16x32_bf16(a2, bfr[ctl][2], c, 0, 0, 0);
                c = __builtin_amdgcn_mfma_f32_16x16x32_bf16(a3, bfr[ctl][3], c, 0, 0, 0);
                acc[rt][ctl] = c;
            }
        }

        #pragma unroll
        for (int rt = 0; rt < 4; ++rt) {
            floatx4 s;
            #pragma unroll
            for (int g = 0; g < 4; ++g)
                s[g] = fmaxf(acc[rt][0][g] + b1v[0], 0.f) * w2v[0]
                     + fmaxf(acc[rt][1][g] + b1v[1], 0.f) * w2v[1];
            #pragma unroll
            for (int m = 1; m < 16; m <<= 1) {
                s[0] += __shfl_xor(s[0], m);
                s[1] += __shfl_xor(s[1], m);
                s[2] += __shfl_xor(s[2], m);
                s[3] += __shfl_xor(s[3], m);
            }
            if (l15 == 0) {
                int rowb = rt * 16 + quad * 4;
                sPart[wave][rowb + 0] = s[0];
                sPart[wave][rowb + 1] = s[1];
                sPart[wave][rowb + 2] = s[2];
                sPart[wave][rowb + 3] = s[3];
            }
        }
        __syncthreads();
        if (tid < 64) {
            float v = sPart[0][tid] + sPart[1][tid] + sPart[2][tid] + sPart[3][tid]
                    + 0.125f * sDot[tid] + b2v;
            out[ebase + tid] = fminf(fmaxf(v, -10.f), 10.f);
        }
        __syncthreads();
    }
}

// ---------------------------------------------------------------------------
extern "C" void kernel_launch(void* const* d_in, const int* in_sizes, int n_in,
                              void* d_out, int out_size, void* d_ws, size_t ws_size,
                              hipStream_t stream)
{
    const float* x_order   = (const float*)d_in[0];
    const float* x_rider   = (const float*)d_in[1];
    const float* edge_attr = (const float*)d_in[2];
    const int*   order_idx = (const int*)d_in[3];
    const int*   rider_idx = (const int*)d_in[4];
    const float* omega     = (const float*)d_in[5];
    const float* Wk = (const float*)d_in[6];  const float* bk = (const float*)d_in[7];
    const float* Wq = (const float*)d_in[8];  const float* bq = (const float*)d_in[9];
    const float* Wv = (const float*)d_in[10]; const float* bv = (const float*)d_in[11];
    const float* We = (const float*)d_in[12];
    const float* Wskip = (const float*)d_in[13]; const float* bskip = (const float*)d_in[14];
    const float* Wp = (const float*)d_in[15]; const float* bp = (const float*)d_in[16];
    const float* W1 = (const float*)d_in[17]; const float* b1 = (const float*)d_in[18];
    const float* W2 = (const float*)d_in[19]; const float* b2 = (const float*)d_in[20];
    float* out = (float*)d_out;

    // layout: kb(12.8M) vb(12.8M) pb(12.8M) spack(16M) then small arrays
    unsigned short* ws_kb = (unsigned short*)d_ws;
    unsigned short* ws_vb = ws_kb + (size_t)NO_N * 64;
    unsigned short* ws_pb = ws_vb + (size_t)NO_N * 64;
    // 3 * 12.8MB = 38.4MB, 16B-aligned
    int4* ws_spack = (int4*)(ws_pb + (size_t)NO_N * 64);
    float* wsf     = (float*)(ws_spack + E_N);
    float* ws_q    = wsf;
    float* ws_skip = ws_q + NR_N * 64;
    float* ws_emb  = ws_skip + NR_N * 64;
    float* ws_t    = ws_emb + NR_N * 64;
    float* ws_b1e  = ws_t + NR_N * 4;
    int* ws_counts  = (int*)(ws_b1e + 128);
    int* ws_offsets = ws_counts + NR_N;
    int* ws_ghist   = ws_offsets + NR_N + 8;
    int* ws_gpre    = ws_ghist + NR_N * SB;

    k_prep_rider<<<NR_N / 4, 256, 0, stream>>>(x_rider, Wq, bq, Wskip, bskip, We,
                                               ws_q, ws_skip, ws_t);
    k_prep_b1eff<<<1, 128, 0, stream>>>(W1, b1, omega, ws_b1e);
    k_kvp<<<1024, 256, 0, stream>>>(x_order, Wk, bk, Wv, bv, Wp, bp,
                                    ws_kb, ws_vb, ws_pb);
    k_hist2<<<SB, 256, 0, stream>>>(rider_idx, ws_ghist);
    k_colscan<<<NR_N, 256, 0, stream>>>(ws_ghist, ws_gpre, ws_counts);
    k_scan<<<1, 1024, 0, stream>>>(ws_counts, ws_offsets);
    k_scatter2<<<SB, 256, 0, stream>>>(rider_idx, order_idx, edge_attr, ws_t,
                                       ws_offsets, ws_gpre, ws_spack);
    k_rider<<<NR_N, 1024, 0, stream>>>(ws_offsets, ws_spack, ws_q,
                                       ws_kb, ws_vb, We, ws_skip, ws_emb);
    k_edge<<<1024, 256, 0, stream>>>(order_idx, rider_idx, ws_pb, ws_emb,
                                     W1, ws_b1e, W2, b2, out);
}

// Round 5
// 319.059 us; speedup vs baseline: 4.5405x; 1.2346x over previous
//
#include <hip/hip_runtime.h>
#include <hip/hip_bf16.h>
#include <math.h>

#define NO_N 100000
#define NR_N 1000
#define E_N  1000000
#define SB     250      // scatter blocks
#define SCHUNK 4000     // edges per scatter block (SB*SCHUNK == E_N)
#define KVP_TILES 1563  // ceil(NO_N/64)

typedef short bf16x8 __attribute__((ext_vector_type(8)));
typedef float floatx4 __attribute__((ext_vector_type(4)));

__device__ __forceinline__ unsigned short bfu(float x) {
    union { __hip_bfloat16 h; unsigned short u; } c;
    c.h = __float2bfloat16(x);
    return c.u;
}
__device__ __forceinline__ float bflo(unsigned int u) {      // low u16 -> f32
    return __uint_as_float(u << 16);
}
__device__ __forceinline__ float bfhi(unsigned int u) {      // high u16 -> f32
    return __uint_as_float(u & 0xffff0000u);
}

// ---------------------------------------------------------------------------
// prep: q[r,h], skip[r,h], t[r,d] = sum_h We[d,h]*q[r,h]
// ---------------------------------------------------------------------------
__global__ __launch_bounds__(256) void k_prep_rider(
    const float* __restrict__ xr,
    const float* __restrict__ Wq, const float* __restrict__ bq,
    const float* __restrict__ Wskip, const float* __restrict__ bskip,
    const float* __restrict__ We,
    float* __restrict__ q, float* __restrict__ skip, float* __restrict__ t)
{
    __shared__ float sx[4][32];
    __shared__ float sq[4][64];
    int tid = threadIdx.x;
    int rbase = blockIdx.x * 4;
    if (tid < 128) {
        int rl = tid >> 5, d = tid & 31;
        int r = rbase + rl;
        sx[rl][d] = (r < NR_N) ? xr[r * 32 + d] : 0.f;
    }
    __syncthreads();
    int rl = tid >> 6, h = tid & 63;
    int r = rbase + rl;
    float aq = bq[h], as = bskip[h];
    #pragma unroll 4
    for (int d = 0; d < 32; ++d) {
        float xv = sx[rl][d];
        aq += xv * Wq[d * 64 + h];
        as += xv * Wskip[d * 64 + h];
    }
    sq[rl][h] = aq;
    if (r < NR_N) { q[r * 64 + h] = aq; skip[r * 64 + h] = as; }
    __syncthreads();
    if (tid < 16) {
        int rl2 = tid >> 2, d = tid & 3;
        int r2 = rbase + rl2;
        float acc = 0.f;
        for (int hh = 0; hh < 64; ++hh) acc += We[d * 64 + hh] * sq[rl2][hh];
        if (r2 < NR_N) t[r2 * 4 + d] = acc;
    }
}

// b1eff[c] = b1[c] + sum_j omega[j] * W1[128+j][c]
__global__ __launch_bounds__(128) void k_prep_b1eff(
    const float* __restrict__ W1, const float* __restrict__ b1,
    const float* __restrict__ omega, float* __restrict__ b1eff)
{
    int c = threadIdx.x;
    float acc = b1[c];
    #pragma unroll 4
    for (int j = 0; j < 32; ++j) acc += omega[j] * W1[(128 + j) * 128 + c];
    b1eff[c] = acc;
}

// ---------------------------------------------------------------------------
// kb,vb,pb (bf16) = x_order @ {Wk,Wv,Wp} + bias  via bf16 MFMA.
// B = [Wk|Wv|Wp] (64x192) persistent in register fragments; wave w owns cols
// [w*48, w*48+48). A = 64-row x tile staged in LDS bf16 (stride 72: 2-way
// bank aliasing only). 8 ds_read_b128 + 24 MFMA per wave-tile.
// ---------------------------------------------------------------------------
__global__ __launch_bounds__(256) void k_kvp(
    const float* __restrict__ x,
    const float* __restrict__ Wk, const float* __restrict__ bk,
    const float* __restrict__ Wv, const float* __restrict__ bv,
    const float* __restrict__ Wp, const float* __restrict__ bp,
    unsigned short* __restrict__ kb, unsigned short* __restrict__ vb,
    unsigned short* __restrict__ pb)
{
    __shared__ __align__(16) unsigned short sX[64 * 72];
    const int tid = threadIdx.x;
    const int wave = tid >> 6, lane = tid & 63;
    const int l15 = lane & 15, quad = lane >> 4;

    // persistent B fragments + per-coltile output routing
    bf16x8 bfr[3][2];
    float bias[3];
    unsigned short* outT[3];
    int colc[3];
    #pragma unroll
    for (int ct = 0; ct < 3; ++ct) {
        int n = wave * 48 + ct * 16 + l15;       // global col 0..191
        int table = n >> 6, c = n & 63;
        const float* W  = (table == 0) ? Wk : (table == 1) ? Wv : Wp;
        const float* bb = (table == 0) ? bk : (table == 1) ? bv : bp;
        bias[ct] = bb[c];
        colc[ct] = c;
        outT[ct] = (table == 0) ? kb : (table == 1) ? vb : pb;
        #pragma unroll
        for (int kf = 0; kf < 2; ++kf) {
            bf16x8 f;
            #pragma unroll
            for (int j = 0; j < 8; ++j)
                f[j] = (short)bfu(W[(size_t)(kf * 32 + quad * 8 + j) * 64 + c]);
            bfr[ct][kf] = f;
        }
    }

    const int srl = tid >> 2;            // staging row 0..63
    const int sqt = (tid & 3) * 16;      // staging col base

    for (int tile = blockIdx.x; tile < KVP_TILES; tile += gridDim.x) {
        int rowbase = tile * 64;
        // ---- stage A tile (fp32 -> bf16) ----
        {
            int row = rowbase + srl;
            unsigned short* dst = sX + srl * 72 + sqt;
            if (row < NO_N) {
                const float4* src = (const float4*)(x + (size_t)row * 64 + sqt);
                #pragma unroll
                for (int i = 0; i < 4; ++i) {
                    float4 a = src[i];
                    ushort4 u = { bfu(a.x), bfu(a.y), bfu(a.z), bfu(a.w) };
                    *(ushort4*)(dst + i * 4) = u;
                }
            } else {
                ushort4 z = {0, 0, 0, 0};
                #pragma unroll
                for (int i = 0; i < 4; ++i) *(ushort4*)(dst + i * 4) = z;
            }
        }
        __syncthreads();

        // ---- MFMA ----
        floatx4 acc[4][3];
        #pragma unroll
        for (int rt = 0; rt < 4; ++rt)
            #pragma unroll
            for (int ct = 0; ct < 3; ++ct)
                acc[rt][ct] = (floatx4){bias[ct], bias[ct], bias[ct], bias[ct]};

        #pragma unroll
        for (int rt = 0; rt < 4; ++rt) {
            const unsigned short* ar = sX + (size_t)(rt * 16 + l15) * 72 + quad * 8;
            bf16x8 a0 = *(const bf16x8*)(ar);
            bf16x8 a1 = *(const bf16x8*)(ar + 32);
            #pragma unroll
            for (int ct = 0; ct < 3; ++ct) {
                floatx4 c = acc[rt][ct];
                c = __builtin_amdgcn_mfma_f32_16x16x32_bf16(a0, bfr[ct][0], c, 0, 0, 0);
                c = __builtin_amdgcn_mfma_f32_16x16x32_bf16(a1, bfr[ct][1], c, 0, 0, 0);
                acc[rt][ct] = c;
            }
        }

        // ---- store (C layout: col=l15, row=quad*4+g) ----
        #pragma unroll
        for (int rt = 0; rt < 4; ++rt) {
            int rb = rowbase + rt * 16 + quad * 4;
            #pragma unroll
            for (int ct = 0; ct < 3; ++ct) {
                unsigned short* o = outT[ct];
                size_t cbase = colc[ct];
                #pragma unroll
                for (int g = 0; g < 4; ++g) {
                    int row = rb + g;
                    if (row < NO_N)
                        o[(size_t)row * 64 + cbase] = bfu(acc[rt][ct][g]);
                }
            }
        }
        __syncthreads();
    }
}

// ---------------------------------------------------------------------------
// CSR build (atomic-free across blocks)
// ---------------------------------------------------------------------------
__global__ __launch_bounds__(256) void k_hist2(const int* __restrict__ ridx,
                                               int* __restrict__ ghist)
{
    __shared__ int hc[NR_N];
    int tid = threadIdx.x, b = blockIdx.x;
    for (int i = tid; i < NR_N; i += 256) hc[i] = 0;
    __syncthreads();
    int s = b * SCHUNK;
    for (int i = s + tid; i < s + SCHUNK; i += 256)
        atomicAdd(&hc[ridx[i]], 1);
    __syncthreads();
    for (int i = tid; i < NR_N; i += 256)
        ghist[i * SB + b] = hc[i];
}

__global__ __launch_bounds__(256) void k_colscan(const int* __restrict__ ghist,
                                                 int* __restrict__ gpre,
                                                 int* __restrict__ counts)
{
    __shared__ int s[256];
    int tid = threadIdx.x, r = blockIdx.x;
    int v = (tid < SB) ? ghist[r * SB + tid] : 0;
    s[tid] = v;
    __syncthreads();
    for (int off = 1; off < 256; off <<= 1) {
        int tv = (tid >= off) ? s[tid - off] : 0;
        __syncthreads();
        s[tid] += tv;
        __syncthreads();
    }
    if (tid < SB) gpre[r * SB + tid] = s[tid] - v;
    if (tid == 255) counts[r] = s[255];
}

__global__ __launch_bounds__(1024) void k_scan(const int* __restrict__ counts,
                                               int* __restrict__ offsets)
{
    __shared__ int s[1024];
    int tid = threadIdx.x;
    int c = (tid < NR_N) ? counts[tid] : 0;
    s[tid] = c;
    __syncthreads();
    for (int off = 1; off < 1024; off <<= 1) {
        int tv = (tid >= off) ? s[tid - off] : 0;
        __syncthreads();
        s[tid] += tv;
        __syncthreads();
    }
    if (tid < NR_N) offsets[tid] = s[tid] - c;
    if (tid == NR_N - 1) offsets[NR_N] = s[tid];
}

__global__ __launch_bounds__(256) void k_scatter2(
    const int* __restrict__ ridx, const int* __restrict__ oidx,
    const float* __restrict__ ea, const float* __restrict__ t,
    const int* __restrict__ offsets, const int* __restrict__ gpre,
    int4* __restrict__ spack)
{
    __shared__ int cur[NR_N];
    int tid = threadIdx.x, b = blockIdx.x;
    for (int i = tid; i < NR_N; i += 256)
        cur[i] = offsets[i] + gpre[i * SB + b];
    __syncthreads();
    int s = b * SCHUNK;
    for (int i = s + tid; i < s + SCHUNK; i += 256) {
        int r = ridx[i];
        float4 e4 = *(const float4*)(ea + (size_t)i * 4);
        float4 t4 = *(const float4*)(t + r * 4);
        float h = e4.x * t4.x + e4.y * t4.y + e4.z * t4.z + e4.w * t4.w;
        int pos = atomicAdd(&cur[r], 1);     // LDS atomic only
        int4 pk;
        pk.x = oidx[i];
        pk.y = __float_as_int(h);
        pk.z = (int)((unsigned)bfu(e4.x) | ((unsigned)bfu(e4.y) << 16));
        pk.w = (int)((unsigned)bfu(e4.z) | ((unsigned)bfu(e4.w) << 16));
        spack[pos] = pk;
    }
}

// ---------------------------------------------------------------------------
// rider embedding (MLP-friendly: independent gathers, no per-edge reduce)
// ---------------------------------------------------------------------------
__global__ __launch_bounds__(1024) void k_rider(
    const int* __restrict__ offsets, const int4* __restrict__ spack,
    const float* __restrict__ q,
    const unsigned short* __restrict__ kb, const unsigned short* __restrict__ vb,
    const float* __restrict__ We, const float* __restrict__ skip,
    float* __restrict__ emb)
{
    __shared__ float sQ[64];
    __shared__ int2 sOX[16][64];
    __shared__ float rv[16][64];
    __shared__ float re4[16][4];
    __shared__ float rd[16];

    int r = blockIdx.x;
    int wave = threadIdx.x >> 6, lane = threadIdx.x & 63;
    if (threadIdx.x < 64) sQ[threadIdx.x] = q[r * 64 + threadIdx.x];
    __syncthreads();

    int beg = offsets[r], end = offsets[r + 1];
    int cnt = end - beg;
    int chunk = (cnt + 15) >> 4;
    int s0 = beg + wave * chunk;
    int s1 = min(s0 + chunk, end);

    float aggv = 0.f, dsum = 0.f;
    float ag0 = 0.f, ag1 = 0.f, ag2 = 0.f, ag3 = 0.f;
    const float2* sQ2 = (const float2*)sQ;

    for (int jb = s0; jb < s1; jb += 64) {
        int j = jb + lane;
        bool valid = (j < s1);
        int4 pk = make_int4(0, 0, 0, 0);
        if (valid) pk = spack[j];
        int oo = pk.x;
        float h = __int_as_float(pk.y);

        const uint4* krow = (const uint4*)(kb + (size_t)oo * 64);
        uint4 K0 = krow[0], K1 = krow[1], K2 = krow[2], K3 = krow[3];
        uint4 K4 = krow[4], K5 = krow[5], K6 = krow[6], K7 = krow[7];
        float acc = h;
        #define DOT8(Kv, base) { \
            float2 qa = sQ2[(base) + 0]; \
            acc = fmaf(bflo(Kv.x), qa.x, acc); acc = fmaf(bfhi(Kv.x), qa.y, acc); \
            float2 qb = sQ2[(base) + 1]; \
            acc = fmaf(bflo(Kv.y), qb.x, acc); acc = fmaf(bfhi(Kv.y), qb.y, acc); \
            float2 qc = sQ2[(base) + 2]; \
            acc = fmaf(bflo(Kv.z), qc.x, acc); acc = fmaf(bfhi(Kv.z), qc.y, acc); \
            float2 qd = sQ2[(base) + 3]; \
            acc = fmaf(bflo(Kv.w), qd.x, acc); acc = fmaf(bfhi(Kv.w), qd.y, acc); }
        DOT8(K0, 0) DOT8(K1, 4) DOT8(K2, 8) DOT8(K3, 12)
        DOT8(K4, 16) DOT8(K5, 20) DOT8(K6, 24) DOT8(K7, 28)
        #undef DOT8

        float exv = valid ? __expf(acc * 0.125f) : 0.f;
        dsum += exv;
        unsigned int ez = (unsigned int)pk.z, ew = (unsigned int)pk.w;
        ag0 = fmaf(exv, bflo(ez), ag0);
        ag1 = fmaf(exv, bfhi(ez), ag1);
        ag2 = fmaf(exv, bflo(ew), ag2);
        ag3 = fmaf(exv, bfhi(ew), ag3);

        sOX[wave][lane] = make_int2(oo, __float_as_int(exv));

        int nn = min(s1 - jb, 64);
        int i = 0;
        for (; i + 8 <= nn; i += 8) {
            int2 x0 = sOX[wave][i + 0], x1 = sOX[wave][i + 1];
            int2 x2 = sOX[wave][i + 2], x3 = sOX[wave][i + 3];
            int2 x4 = sOX[wave][i + 4], x5 = sOX[wave][i + 5];
            int2 x6 = sOX[wave][i + 6], x7 = sOX[wave][i + 7];
            unsigned short u0 = vb[(size_t)x0.x * 64 + lane];
            unsigned short u1 = vb[(size_t)x1.x * 64 + lane];
            unsigned short u2 = vb[(size_t)x2.x * 64 + lane];
            unsigned short u3 = vb[(size_t)x3.x * 64 + lane];
            unsigned short u4 = vb[(size_t)x4.x * 64 + lane];
            unsigned short u5 = vb[(size_t)x5.x * 64 + lane];
            unsigned short u6 = vb[(size_t)x6.x * 64 + lane];
            unsigned short u7 = vb[(size_t)x7.x * 64 + lane];
            aggv = fmaf(__int_as_float(x0.y), __uint_as_float((unsigned int)u0 << 16), aggv);
            aggv = fmaf(__int_as_float(x1.y), __uint_as_float((unsigned int)u1 << 16), aggv);
            aggv = fmaf(__int_as_float(x2.y), __uint_as_float((unsigned int)u2 << 16), aggv);
            aggv = fmaf(__int_as_float(x3.y), __uint_as_float((unsigned int)u3 << 16), aggv);
            aggv = fmaf(__int_as_float(x4.y), __uint_as_float((unsigned int)u4 << 16), aggv);
            aggv = fmaf(__int_as_float(x5.y), __uint_as_float((unsigned int)u5 << 16), aggv);
            aggv = fmaf(__int_as_float(x6.y), __uint_as_float((unsigned int)u6 << 16), aggv);
            aggv = fmaf(__int_as_float(x7.y), __uint_as_float((unsigned int)u7 << 16), aggv);
        }
        for (; i < nn; ++i) {
            int2 xx = sOX[wave][i];
            unsigned short uu = vb[(size_t)xx.x * 64 + lane];
            aggv = fmaf(__int_as_float(xx.y), __uint_as_float((unsigned int)uu << 16), aggv);
        }
    }

    #pragma unroll
    for (int m = 1; m < 64; m <<= 1) {
        dsum += __shfl_xor(dsum, m);
        ag0 += __shfl_xor(ag0, m);
        ag1 += __shfl_xor(ag1, m);
        ag2 += __shfl_xor(ag2, m);
        ag3 += __shfl_xor(ag3, m);
    }

    rv[wave][lane] = aggv;
    if (lane == 0) {
        rd[wave] = dsum;
        re4[wave][0] = ag0; re4[wave][1] = ag1;
        re4[wave][2] = ag2; re4[wave][3] = ag3;
    }
    __syncthreads();
    if (threadIdx.x < 64) {
        int l = threadIdx.x;
        float av = 0.f, ds = 0.f, a0 = 0.f, a1 = 0.f, a2 = 0.f, a3 = 0.f;
        #pragma unroll 4
        for (int w = 0; w < 16; ++w) {
            av += rv[w][l]; ds += rd[w];
            a0 += re4[w][0]; a1 += re4[w][1]; a2 += re4[w][2]; a3 += re4[w][3];
        }
        float corr = a0 * We[0 * 64 + l] + a1 * We[1 * 64 + l]
                   + a2 * We[2 * 64 + l] + a3 * We[3 * 64 + l];
        emb[r * 64 + l] = (av + corr) / (ds + 1e-16f) + skip[r * 64 + l];
    }
}

// ---------------------------------------------------------------------------
// per-edge scoring via bf16 MFMA (W1 persistent in register fragments).
// ---------------------------------------------------------------------------
__global__ __launch_bounds__(256, 4) void k_edge(
    const int* __restrict__ oidx, const int* __restrict__ ridx,
    const unsigned short* __restrict__ pb, const float* __restrict__ emb,
    const float* __restrict__ W1, const float* __restrict__ b1eff,
    const float* __restrict__ W2, const float* __restrict__ b2,
    float* __restrict__ out)
{
    __shared__ __align__(16) unsigned short sA[64 * 136];
    __shared__ float sDot[64];
    __shared__ float sPart[4][64];

    const int tid = threadIdx.x;
    const int wave = tid >> 6;
    const int lane = tid & 63;
    const int l15 = lane & 15;
    const int quad = lane >> 4;

    bf16x8 bfr[2][4];
    float b1v[2], w2v[2];
    #pragma unroll
    for (int ctl = 0; ctl < 2; ++ctl) {
        int n = wave * 32 + ctl * 16 + l15;
        b1v[ctl] = b1eff[n];
        w2v[ctl] = W2[n];
        #pragma unroll
        for (int kc = 0; kc < 4; ++kc) {
            int k0 = kc * 32 + quad * 8;
            bf16x8 f;
            #pragma unroll
            for (int j = 0; j < 8; ++j)
                f[j] = (short)bfu(W1[(size_t)(k0 + j) * 128 + n]);
            bfr[ctl][kc] = f;
        }
    }
    float b2v = b2[0];

    const int el = tid >> 2;
    const int qd = (tid & 3) * 16;

    for (int tile = blockIdx.x; tile < E_N / 64; tile += gridDim.x) {
        int ebase = tile * 64;
        {
            int e = ebase + el;
            int o = oidx[e];
            int r = ridx[e];
            const uint2* po = (const uint2*)(pb + (size_t)o * 64 + qd);
            const float4* pr = (const float4*)(emb + (size_t)r * 64 + qd);
            unsigned short* rowA = sA + el * 136;
            float dotp = 0.f;
            #pragma unroll
            for (int i = 0; i < 4; ++i) {
                uint2 a = po[i];
                float4 b = pr[i];
                dotp += bflo(a.x) * b.x + bfhi(a.x) * b.y
                      + bflo(a.y) * b.z + bfhi(a.y) * b.w;
                *(uint2*)(rowA + qd + i * 4) = a;
                ushort4 ub = { bfu(b.x), bfu(b.y), bfu(b.z), bfu(b.w) };
                *(ushort4*)(rowA + 64 + qd + i * 4) = ub;
            }
            dotp += __shfl_xor(dotp, 1);
            dotp += __shfl_xor(dotp, 2);
            if ((tid & 3) == 0) sDot[el] = dotp;
        }
        __syncthreads();

        floatx4 acc[4][2];
        #pragma unroll
        for (int rt = 0; rt < 4; ++rt)
            #pragma unroll
            for (int ctl = 0; ctl < 2; ++ctl)
                acc[rt][ctl] = (floatx4){0.f, 0.f, 0.f, 0.f};

        #pragma unroll
        for (int rt = 0; rt < 4; ++rt) {
            const unsigned short* ar = sA + (size_t)(rt * 16 + l15) * 136 + quad * 8;
            bf16x8 a0 = *(const bf16x8*)(ar);
            bf16x8 a1 = *(const bf16x8*)(ar + 32);
            bf16x8 a2 = *(const bf16x8*)(ar + 64);
            bf16x8 a3 = *(const bf16x8*)(ar + 96);
            #pragma unroll
            for (int ctl = 0; ctl < 2; ++ctl) {
                floatx4 c = acc[rt][ctl];
                c = __builtin_amdgcn_mfma_f32_16x16x32_bf16(a0, bfr[ctl][0], c, 0, 0, 0);
                c = __builtin_amdgcn_mfma_f32_16x16x32_bf16(a1, bfr[ctl][1], c, 0, 0, 0);
                c = __builtin_amdgcn_mfma_f32_16x16x32_bf16(a2, bfr[ctl][2], c, 0, 0, 0);
                c = __builtin_amdgcn_mfma_f32_16x16x32_bf16(a3, bfr[ctl][3], c, 0, 0, 0);
                acc[rt][ctl] = c;
            }
        }

        #pragma unroll
        for (int rt = 0; rt < 4; ++rt) {
            floatx4 s;
            #pragma unroll
            for (int g = 0; g < 4; ++g)
                s[g] = fmaxf(acc[rt][0][g] + b1v[0], 0.f) * w2v[0]
                     + fmaxf(acc[rt][1][g] + b1v[1], 0.f) * w2v[1];
            #pragma unroll
            for (int m = 1; m < 16; m <<= 1) {
                s[0] += __shfl_xor(s[0], m);
                s[1] += __shfl_xor(s[1], m);
                s[2] += __shfl_xor(s[2], m);
                s[3] += __shfl_xor(s[3], m);
            }
            if (l15 == 0) {
                int rowb = rt * 16 + quad * 4;
                sPart[wave][rowb + 0] = s[0];
                sPart[wave][rowb + 1] = s[1];
                sPart[wave][rowb + 2] = s[2];
                sPart[wave][rowb + 3] = s[3];
            }
        }
        __syncthreads();
        if (tid < 64) {
            float v = sPart[0][tid] + sPart[1][tid] + sPart[2][tid] + sPart[3][tid]
                    + 0.125f * sDot[tid] + b2v;
            out[ebase + tid] = fminf(fmaxf(v, -10.f), 10.f);
        }
        __syncthreads();
    }
}

// ---------------------------------------------------------------------------
extern "C" void kernel_launch(void* const* d_in, const int* in_sizes, int n_in,
                              void* d_out, int out_size, void* d_ws, size_t ws_size,
                              hipStream_t stream)
{
    const float* x_order   = (const float*)d_in[0];
    const float* x_rider   = (const float*)d_in[1];
    const float* edge_attr = (const float*)d_in[2];
    const int*   order_idx = (const int*)d_in[3];
    const int*   rider_idx = (const int*)d_in[4];
    const float* omega     = (const float*)d_in[5];
    const float* Wk = (const float*)d_in[6];  const float* bk = (const float*)d_in[7];
    const float* Wq = (const float*)d_in[8];  const float* bq = (const float*)d_in[9];
    const float* Wv = (const float*)d_in[10]; const float* bv = (const float*)d_in[11];
    const float* We = (const float*)d_in[12];
    const float* Wskip = (const float*)d_in[13]; const float* bskip = (const float*)d_in[14];
    const float* Wp = (const float*)d_in[15]; const float* bp = (const float*)d_in[16];
    const float* W1 = (const float*)d_in[17]; const float* b1 = (const float*)d_in[18];
    const float* W2 = (const float*)d_in[19]; const float* b2 = (const float*)d_in[20];
    float* out = (float*)d_out;

    unsigned short* ws_kb = (unsigned short*)d_ws;
    unsigned short* ws_vb = ws_kb + (size_t)NO_N * 64;
    unsigned short* ws_pb = ws_vb + (size_t)NO_N * 64;
    int4* ws_spack = (int4*)(ws_pb + (size_t)NO_N * 64);
    float* wsf     = (float*)(ws_spack + E_N);
    float* ws_q    = wsf;
    float* ws_skip = ws_q + NR_N * 64;
    float* ws_emb  = ws_skip + NR_N * 64;
    float* ws_t    = ws_emb + NR_N * 64;
    float* ws_b1e  = ws_t + NR_N * 4;
    int* ws_counts  = (int*)(ws_b1e + 128);
    int* ws_offsets = ws_counts + NR_N;
    int* ws_ghist   = ws_offsets + NR_N + 8;
    int* ws_gpre    = ws_ghist + NR_N * SB;

    k_prep_rider<<<NR_N / 4, 256, 0, stream>>>(x_rider, Wq, bq, Wskip, bskip, We,
                                               ws_q, ws_skip, ws_t);
    k_prep_b1eff<<<1, 128, 0, stream>>>(W1, b1, omega, ws_b1e);
    k_kvp<<<521, 256, 0, stream>>>(x_order, Wk, bk, Wv, bv, Wp, bp,
                                   ws_kb, ws_vb, ws_pb);
    k_hist2<<<SB, 256, 0, stream>>>(rider_idx, ws_ghist);
    k_colscan<<<NR_N, 256, 0, stream>>>(ws_ghist, ws_gpre, ws_counts);
    k_scan<<<1, 1024, 0, stream>>>(ws_counts, ws_offsets);
    k_scatter2<<<SB, 256, 0, stream>>>(rider_idx, order_idx, edge_attr, ws_t,
                                       ws_offsets, ws_gpre, ws_spack);
    k_rider<<<NR_N, 1024, 0, stream>>>(ws_offsets, ws_spack, ws_q,
                                       ws_kb, ws_vb, We, ws_skip, ws_emb);
    k_edge<<<1024, 256, 0, stream>>>(order_idx, rider_idx, ws_pb, ws_emb,
                                     W1, ws_b1e, W2, b2, out);
}